// Round 3
// baseline (12368.625 us; speedup 1.0000x reference)
//
#include <hip/hip_runtime.h>
#include <hip/hip_bf16.h>
#include <math.h>

#define NEG_SLOPE 0.2f

__device__ __forceinline__ float wredmax(float v){
  #pragma unroll
  for (int o = 32; o; o >>= 1) v = fmaxf(v, __shfl_xor(v, o, 64));
  return v;
}
__device__ __forceinline__ float wredsum(float v){
  #pragma unroll
  for (int o = 32; o; o >>= 1) v += __shfl_xor(v, o, 64);
  return v;
}
__device__ __forceinline__ float lrelu(float x){ return x >= 0.f ? x : NEG_SLOPE * x; }
__device__ __forceinline__ unsigned short f2bf(float f){
  __hip_bfloat16 h = __float2bfloat16(f);
  return *(unsigned short*)&h;
}
__device__ __forceinline__ float bf2f(unsigned short u){
  return __uint_as_float((unsigned)u << 16);
}

// ---- CSR construction ------------------------------------------------------
__global__ void k_deg_attr(const int* __restrict__ ei, const float* __restrict__ ea,
                           int* __restrict__ deg, float* __restrict__ loop_attr, int E){
  int idx = blockIdx.x * 256 + threadIdx.x;
  int e = idx >> 5, k = idx & 31;
  if (e >= E) return;
  int dst = ei[E + e];
  atomicAdd(&loop_attr[dst * 32 + k], ea[(size_t)e * 32 + k]);
  if (k == 0) atomicAdd(&deg[dst], 1);
}

__global__ void k_loop_div(float* __restrict__ loop_attr, const int* __restrict__ deg, int N){
  int idx = blockIdx.x * 256 + threadIdx.x;
  if (idx >= N * 32) return;
  float d = (float)max(deg[idx >> 5], 1);
  loop_attr[idx] /= d;
}

// row width = deg[n] + 1 (self loop).  N = 16384 = 256 * 64, single block scan.
__global__ void k_scan(const int* __restrict__ deg, int* __restrict__ row_start, int N){
  __shared__ int s[256];
  int t = threadIdx.x;
  int base = t * 64;
  int sum = 0;
  for (int i = 0; i < 64; ++i) sum += deg[base + i] + 1;
  s[t] = sum;
  __syncthreads();
  for (int off = 1; off < 256; off <<= 1){
    int v = (t >= off) ? s[t - off] : 0;
    __syncthreads();
    s[t] += v;
    __syncthreads();
  }
  int run = s[t] - sum;   // exclusive
  for (int i = 0; i < 64; ++i){ row_start[base + i] = run; run += deg[base + i] + 1; }
  if (t == 255) row_start[N] = run;
}

__global__ void k_csr_self(const int* __restrict__ row_start, int* __restrict__ csr_src,
                           int* __restrict__ pos_map, int N, int E){
  int n = blockIdx.x * 256 + threadIdx.x;
  if (n >= N) return;
  int p = row_start[n];
  csr_src[p] = n;          // self loop in slot 0
  pos_map[E + n] = p;
}

__global__ void k_csr_fill(const int* __restrict__ ei, const int* __restrict__ row_start,
                           int* __restrict__ fill, int* __restrict__ csr_src,
                           int* __restrict__ pos_map, int E){
  int e = blockIdx.x * 256 + threadIdx.x;
  if (e >= E) return;
  int dst = ei[E + e];
  int p = row_start[dst] + 1 + atomicAdd(&fill[dst], 1);
  csr_src[p] = ei[e];
  pos_map[e] = p;
}

// ea_perm[pos_map[e]] = bf16(concat(ea, loop_attr)[e])   (32 vals per row)
__global__ void k_permute_ea(const float* __restrict__ ea, const float* __restrict__ loop_attr,
                             const int* __restrict__ pos_map, unsigned short* __restrict__ ea_perm,
                             int E, int N){
  int idx = blockIdx.x * 256 + threadIdx.x;   // one float4 per thread
  int e = idx >> 3, q = idx & 7;
  if (e >= E + N) return;
  const float* srcp = (e < E) ? ea + (size_t)e * 32 : loop_attr + (size_t)(e - E) * 32;
  float4 v = ((const float4*)srcp)[q];
  int pos = pos_map[e];
  ushort4 o;
  o.x = f2bf(v.x); o.y = f2bf(v.y); o.z = f2bf(v.z); o.w = f2bf(v.w);
  *(ushort4*)&ea_perm[(size_t)pos * 32 + q * 4] = o;
}

// ---- fp32 GEMM: C[M,N] = A[M,K] @ B[K,N] + bias  (M%64==0, N%64==0, K%16==0)
__device__ __forceinline__ void store4(float* p, float4 v){ *(float4*)p = v; }
__device__ __forceinline__ void store4(unsigned short* p, float4 v){
  ushort4 o; o.x = f2bf(v.x); o.y = f2bf(v.y); o.z = f2bf(v.z); o.w = f2bf(v.w);
  *(ushort4*)p = o;
}

template<typename OutT>
__global__ __launch_bounds__(256) void k_gemm_bias(const float* __restrict__ A,
    const float* __restrict__ B, const float* __restrict__ bias, OutT* __restrict__ C,
    int M, int N, int K){
  __shared__ float As[16][64];
  __shared__ float Bs[16][64];
  int t = threadIdx.x;
  int bx = blockIdx.x, by = blockIdx.y;
  int tx = t & 15, ty = t >> 4;
  int la_r = t >> 2;            // 0..63   (m within tile)
  int la_c = (t & 3) << 2;      // 0,4,8,12 (k within tile)
  int lb_r = t >> 4;            // 0..15   (k within tile)
  int lb_c = (t & 15) << 2;     // 0..60   (n within tile)
  const float* Ap = A + (size_t)(by * 64 + la_r) * K + la_c;
  const float* Bp = B + (size_t)lb_r * N + bx * 64 + lb_c;
  float acc[4][4] = {};
  for (int k0 = 0; k0 < K; k0 += 16){
    float4 a4 = *(const float4*)(Ap + k0);
    float4 b4 = *(const float4*)(Bp + (size_t)k0 * N);
    __syncthreads();
    As[la_c + 0][la_r] = a4.x;
    As[la_c + 1][la_r] = a4.y;
    As[la_c + 2][la_r] = a4.z;
    As[la_c + 3][la_r] = a4.w;
    *(float4*)&Bs[lb_r][lb_c] = b4;
    __syncthreads();
    #pragma unroll
    for (int kk = 0; kk < 16; ++kk){
      float4 av = *(float4*)&As[kk][ty << 2];
      float4 bv = *(float4*)&Bs[kk][tx << 2];
      acc[0][0] += av.x * bv.x; acc[0][1] += av.x * bv.y; acc[0][2] += av.x * bv.z; acc[0][3] += av.x * bv.w;
      acc[1][0] += av.y * bv.x; acc[1][1] += av.y * bv.y; acc[1][2] += av.y * bv.z; acc[1][3] += av.y * bv.w;
      acc[2][0] += av.z * bv.x; acc[2][1] += av.z * bv.y; acc[2][2] += av.z * bv.z; acc[2][3] += av.z * bv.w;
      acc[3][0] += av.w * bv.x; acc[3][1] += av.w * bv.y; acc[3][2] += av.w * bv.z; acc[3][3] += av.w * bv.w;
    }
  }
  int m0 = by * 64 + (ty << 2);
  int n0 = bx * 64 + (tx << 2);
  float4 bi = *(const float4*)&bias[n0];
  #pragma unroll
  for (int i = 0; i < 4; ++i){
    float4 o = make_float4(acc[i][0] + bi.x, acc[i][1] + bi.y, acc[i][2] + bi.z, acc[i][3] + bi.w);
    store4(&C[(size_t)(m0 + i) * N + n0], o);
  }
}

// ---- fused logit + online-softmax + aggregation (one wave per dst node) ----
// out[n] = relu( sum_e alpha_e * xl[src_e] + bc ),
// alpha = softmax_e( sum_j att_j * lrelu(xl[src][j] + xr[n][j] + (ea_e@We)[j]) )
// ea@We computed on the fly: We bf16 in LDS, ea bf16 per edge (lanes 0..31),
// broadcast via readlane-shfl.
template<int CH>   // FO = CH*256
__global__ __launch_bounds__(512, 4) void k_fused_agg(const float* __restrict__ XL,
    const unsigned short* __restrict__ XRb, const unsigned short* __restrict__ ea_perm,
    const float* __restrict__ We, const int* __restrict__ csr_src,
    const int* __restrict__ row_start, const float* __restrict__ att,
    const float* __restrict__ bc, float* __restrict__ out){
  const int FO = CH * 256;
  __shared__ unsigned short We_s[32 * CH * 256];
  int t = threadIdx.x;
  for (int idx = t; idx < 32 * FO; idx += 512) We_s[idx] = f2bf(We[idx]);
  __syncthreads();
  int lane = t & 63;
  int wave = t >> 6;
  int n = blockIdx.x * 8 + wave;
  int rs = row_start[n], re = row_start[n + 1];
  int jj = lane << 2;
  float4 xr[CH], at4[CH], acc[CH];
  #pragma unroll
  for (int c = 0; c < CH; ++c){
    ushort4 ur = *(const ushort4*)&XRb[(size_t)n * FO + (c << 8) + jj];
    xr[c] = make_float4(bf2f(ur.x), bf2f(ur.y), bf2f(ur.z), bf2f(ur.w));
    at4[c] = *(const float4*)&att[(c << 8) + jj];
    acc[c] = make_float4(0.f, 0.f, 0.f, 0.f);
  }
  float m = -1e30f, den = 0.f;
  for (int i = rs; i < re; ++i){
    int s = csr_src[i];
    float aval = (lane < 32) ? bf2f(ea_perm[(size_t)i * 32 + lane]) : 0.f;
    const float* xp = XL + (size_t)s * FO;
    float4 xl[CH], ew[CH];
    #pragma unroll
    for (int c = 0; c < CH; ++c){
      xl[c] = *(const float4*)&xp[(c << 8) + jj];
      ew[c] = make_float4(0.f, 0.f, 0.f, 0.f);
    }
    #pragma unroll
    for (int k = 0; k < 32; ++k){
      float a = __shfl(aval, k, 64);
      #pragma unroll
      for (int c = 0; c < CH; ++c){
        uint2 u = *(const uint2*)&We_s[k * FO + (c << 8) + jj];
        ew[c].x += a * __uint_as_float(u.x << 16);
        ew[c].y += a * __uint_as_float(u.x & 0xffff0000u);
        ew[c].z += a * __uint_as_float(u.y << 16);
        ew[c].w += a * __uint_as_float(u.y & 0xffff0000u);
      }
    }
    float tt = 0.f;
    #pragma unroll
    for (int c = 0; c < CH; ++c){
      float v0 = xl[c].x + xr[c].x + ew[c].x;
      float v1 = xl[c].y + xr[c].y + ew[c].y;
      float v2 = xl[c].z + xr[c].z + ew[c].z;
      float v3 = xl[c].w + xr[c].w + ew[c].w;
      tt += at4[c].x * lrelu(v0) + at4[c].y * lrelu(v1) + at4[c].z * lrelu(v2) + at4[c].w * lrelu(v3);
    }
    tt = wredsum(tt);
    float mn = fmaxf(m, tt);
    float scale = __expf(m - mn);   // first iter: exp(-huge) = 0
    float f = __expf(tt - mn);
    den = den * scale + f;
    #pragma unroll
    for (int c = 0; c < CH; ++c){
      acc[c].x = acc[c].x * scale + f * xl[c].x;
      acc[c].y = acc[c].y * scale + f * xl[c].y;
      acc[c].z = acc[c].z * scale + f * xl[c].z;
      acc[c].w = acc[c].w * scale + f * xl[c].w;
    }
    m = mn;
  }
  float inv = 1.f / den;
  #pragma unroll
  for (int c = 0; c < CH; ++c){
    float4 b4 = *(const float4*)&bc[(c << 8) + jj];
    float4 o = make_float4(fmaxf(acc[c].x * inv + b4.x, 0.f),
                           fmaxf(acc[c].y * inv + b4.y, 0.f),
                           fmaxf(acc[c].z * inv + b4.z, 0.f),
                           fmaxf(acc[c].w * inv + b4.w, 0.f));
    *(float4*)&out[(size_t)n * FO + (c << 8) + jj] = o;
  }
}

// ---- pooling + head --------------------------------------------------------
__global__ void k_pool(const float* __restrict__ H, const int* __restrict__ batch,
                       float* __restrict__ psum, float* __restrict__ pcnt){
  int n = blockIdx.x;
  int j = threadIdx.x;
  int g = batch[n];
  atomicAdd(&psum[g * 256 + j], H[(size_t)n * 256 + j]);
  if (j == 0) atomicAdd(&pcnt[g], 1.f);
}

__global__ void k_fc1(const float* __restrict__ psum, const float* __restrict__ pcnt,
                      const float* __restrict__ w, const float* __restrict__ b,
                      float* __restrict__ z){
  int idx = blockIdx.x * 256 + threadIdx.x;
  if (idx >= 128 * 64) return;
  int g = idx >> 6, j = idx & 63;
  float acc = 0.f;
  for (int k = 0; k < 256; ++k) acc += psum[g * 256 + k] * w[k * 64 + j];
  z[idx] = acc / fmaxf(pcnt[g], 1.f) + b[j];
}

__global__ void k_head(const float* __restrict__ z, const float* __restrict__ bn_g,
                       const float* __restrict__ bn_b, const float* __restrict__ w2,
                       const float* __restrict__ b2, float* __restrict__ out){
  __shared__ float mu_s[64], is_s[64];
  int t = threadIdx.x;  // 128 threads
  if (t < 64){
    float mu = 0.f, m2 = 0.f;
    for (int g = 0; g < 128; ++g){ float v = z[g * 64 + t]; mu += v; m2 += v * v; }
    mu /= 128.f; m2 /= 128.f;
    float var = m2 - mu * mu;
    mu_s[t] = mu;
    is_s[t] = rsqrtf(var + 1e-5f);
  }
  __syncthreads();
  float o = b2[0];
  for (int j = 0; j < 64; ++j){
    float v = (z[t * 64 + j] - mu_s[j]) * is_s[j] * bn_g[j] + bn_b[j];
    o += fmaxf(v, 0.f) * w2[j];
  }
  out[t] = o;
}

extern "C" void kernel_launch(void* const* d_in, const int* in_sizes, int n_in,
                              void* d_out, int out_size, void* d_ws, size_t ws_size,
                              hipStream_t stream){
  const int N = 16384, E = 131072, Eaug = E + N, NG = 128;
  const float* x     = (const float*)d_in[0];
  const int*   ei    = (const int*)  d_in[1];
  const float* ea    = (const float*)d_in[2];
  const int*   batch = (const int*)  d_in[3];
  const float* Wl[3]  = {(const float*)d_in[4],  (const float*)d_in[11], (const float*)d_in[18]};
  const float* bl[3]  = {(const float*)d_in[5],  (const float*)d_in[12], (const float*)d_in[19]};
  const float* Wr[3]  = {(const float*)d_in[6],  (const float*)d_in[13], (const float*)d_in[20]};
  const float* br[3]  = {(const float*)d_in[7],  (const float*)d_in[14], (const float*)d_in[21]};
  const float* We[3]  = {(const float*)d_in[8],  (const float*)d_in[15], (const float*)d_in[22]};
  const float* att[3] = {(const float*)d_in[9],  (const float*)d_in[16], (const float*)d_in[23]};
  const float* bc[3]  = {(const float*)d_in[10], (const float*)d_in[17], (const float*)d_in[24]};
  const float* fc1_w = (const float*)d_in[25];
  const float* fc1_b = (const float*)d_in[26];
  const float* bn_g  = (const float*)d_in[27];
  const float* bn_b  = (const float*)d_in[28];
  const float* fc2_w = (const float*)d_in[29];
  const float* fc2_b = (const float*)d_in[30];
  float* out = (float*)d_out;

  char* wsb = (char*)d_ws;
  size_t off = 0;
  auto alloc = [&](size_t bytes) -> char* {
    char* p = wsb + off;
    off = (off + bytes + 255) & ~(size_t)255;
    return p;
  };
  int*   deg       = (int*)  alloc((size_t)N * 4);
  int*   fill      = (int*)  alloc((size_t)N * 4);
  int*   row_start = (int*)  alloc((size_t)(N + 1) * 4);
  float* loop_attr = (float*)alloc((size_t)N * 32 * 4);
  int*   csr_src   = (int*)  alloc((size_t)Eaug * 4);
  int*   pos_map   = (int*)  alloc((size_t)Eaug * 4);
  unsigned short* ea_perm = (unsigned short*)alloc((size_t)Eaug * 32 * 2);
  float* XL        = (float*)alloc((size_t)N * 1024 * 4);
  unsigned short* XRb = (unsigned short*)alloc((size_t)N * 1024 * 2);
  float* buf1      = (float*)alloc((size_t)N * 512 * 4);   // L1 out (512) / L3 out (256)
  float* buf2      = (float*)alloc((size_t)N * 1024 * 4);  // L2 out
  float* psum      = (float*)alloc((size_t)NG * 256 * 4);
  float* pcnt      = (float*)alloc((size_t)NG * 4);
  float* zbuf      = (float*)alloc((size_t)NG * 64 * 4);
  // total ~205 MB (round-1's 228 MB footprint passed)

  hipMemsetAsync(deg, 0, (size_t)N * 4, stream);
  hipMemsetAsync(fill, 0, (size_t)N * 4, stream);
  hipMemsetAsync(loop_attr, 0, (size_t)N * 32 * 4, stream);
  hipMemsetAsync(psum, 0, (size_t)NG * 256 * 4, stream);
  hipMemsetAsync(pcnt, 0, (size_t)NG * 4, stream);

  k_deg_attr<<<(E * 32) / 256, 256, 0, stream>>>(ei, ea, deg, loop_attr, E);
  k_loop_div<<<(N * 32) / 256, 256, 0, stream>>>(loop_attr, deg, N);
  k_scan<<<1, 256, 0, stream>>>(deg, row_start, N);
  k_csr_self<<<N / 256, 256, 0, stream>>>(row_start, csr_src, pos_map, N, E);
  k_csr_fill<<<E / 256, 256, 0, stream>>>(ei, row_start, fill, csr_src, pos_map, E);
  k_permute_ea<<<(Eaug * 8) / 256, 256, 0, stream>>>(ea, loop_attr, pos_map, ea_perm, E, N);

  const int fin[3] = {256, 512, 1024};
  const int fo[3]  = {512, 1024, 256};
  float* outbuf[3] = {buf1, buf2, buf1};
  const float* Xin = x;
  for (int L = 0; L < 3; ++L){
    int FI = fin[L], FO = fo[L];
    dim3 ggrid(FO / 64, N / 64);
    k_gemm_bias<float><<<ggrid, 256, 0, stream>>>(Xin, Wl[L], bl[L], XL, N, FO, FI);
    k_gemm_bias<unsigned short><<<ggrid, 256, 0, stream>>>(Xin, Wr[L], br[L], XRb, N, FO, FI);
    if (FO == 256)
      k_fused_agg<1><<<N / 8, 512, 0, stream>>>(XL, XRb, ea_perm, We[L], csr_src, row_start, att[L], bc[L], outbuf[L]);
    else if (FO == 512)
      k_fused_agg<2><<<N / 8, 512, 0, stream>>>(XL, XRb, ea_perm, We[L], csr_src, row_start, att[L], bc[L], outbuf[L]);
    else
      k_fused_agg<4><<<N / 8, 512, 0, stream>>>(XL, XRb, ea_perm, We[L], csr_src, row_start, att[L], bc[L], outbuf[L]);
    Xin = outbuf[L];
  }
  k_pool<<<N, 256, 0, stream>>>(buf1, batch, psum, pcnt);
  k_fc1<<<32, 256, 0, stream>>>(psum, pcnt, fc1_w, fc1_b, zbuf);
  k_head<<<1, 128, 0, stream>>>(zbuf, bn_g, bn_b, fc2_w, fc2_b, out);
}

// Round 4
// 2477.829 us; speedup vs baseline: 4.9917x; 4.9917x over previous
//
#include <hip/hip_runtime.h>
#include <hip/hip_bf16.h>
#include <math.h>

#define NEG_SLOPE 0.2f

__device__ __forceinline__ float wredmax(float v){
  #pragma unroll
  for (int o = 32; o; o >>= 1) v = fmaxf(v, __shfl_xor(v, o, 64));
  return v;
}
__device__ __forceinline__ float wredsum(float v){
  #pragma unroll
  for (int o = 32; o; o >>= 1) v += __shfl_xor(v, o, 64);
  return v;
}
__device__ __forceinline__ float lrelu(float x){ return x >= 0.f ? x : NEG_SLOPE * x; }
__device__ __forceinline__ unsigned short f2bf(float f){
  __hip_bfloat16 h = __float2bfloat16(f);
  return *(unsigned short*)&h;
}
__device__ __forceinline__ float bf2f(unsigned short u){
  return __uint_as_float((unsigned)u << 16);
}

// vectorized load/store helpers (fp32 or bf16 behind a common float4 view)
__device__ __forceinline__ float4 load4(const float* p){ return *(const float4*)p; }
__device__ __forceinline__ float4 load4(const unsigned short* p){
  ushort4 u = *(const ushort4*)p;
  return make_float4(bf2f(u.x), bf2f(u.y), bf2f(u.z), bf2f(u.w));
}
__device__ __forceinline__ void store4(float* p, float4 v){ *(float4*)p = v; }
__device__ __forceinline__ void store4(unsigned short* p, float4 v){
  ushort4 o; o.x = f2bf(v.x); o.y = f2bf(v.y); o.z = f2bf(v.z); o.w = f2bf(v.w);
  *(ushort4*)p = o;
}

// ---- CSR construction ------------------------------------------------------
__global__ void k_deg_attr(const int* __restrict__ ei, const float* __restrict__ ea,
                           int* __restrict__ deg, float* __restrict__ loop_attr, int E){
  int idx = blockIdx.x * 256 + threadIdx.x;
  int e = idx >> 5, k = idx & 31;
  if (e >= E) return;
  int dst = ei[E + e];
  atomicAdd(&loop_attr[dst * 32 + k], ea[(size_t)e * 32 + k]);
  if (k == 0) atomicAdd(&deg[dst], 1);
}

__global__ void k_loop_div(float* __restrict__ loop_attr, const int* __restrict__ deg, int N){
  int idx = blockIdx.x * 256 + threadIdx.x;
  if (idx >= N * 32) return;
  float d = (float)max(deg[idx >> 5], 1);
  loop_attr[idx] /= d;
}

// row width = deg[n] + 1 (self loop).  N = 16384 = 256 * 64, single block scan.
__global__ void k_scan(const int* __restrict__ deg, int* __restrict__ row_start, int N){
  __shared__ int s[256];
  int t = threadIdx.x;
  int base = t * 64;
  int sum = 0;
  for (int i = 0; i < 64; ++i) sum += deg[base + i] + 1;
  s[t] = sum;
  __syncthreads();
  for (int off = 1; off < 256; off <<= 1){
    int v = (t >= off) ? s[t - off] : 0;
    __syncthreads();
    s[t] += v;
    __syncthreads();
  }
  int run = s[t] - sum;   // exclusive
  for (int i = 0; i < 64; ++i){ row_start[base + i] = run; run += deg[base + i] + 1; }
  if (t == 255) row_start[N] = run;
}

__global__ void k_csr_self(const int* __restrict__ row_start, int* __restrict__ csr_src,
                           int* __restrict__ pos_map, int N, int E){
  int n = blockIdx.x * 256 + threadIdx.x;
  if (n >= N) return;
  int p = row_start[n];
  csr_src[p] = n;          // self loop in slot 0
  pos_map[E + n] = p;
}

__global__ void k_csr_fill(const int* __restrict__ ei, const int* __restrict__ row_start,
                           int* __restrict__ fill, int* __restrict__ csr_src,
                           int* __restrict__ pos_map, int E){
  int e = blockIdx.x * 256 + threadIdx.x;
  if (e >= E) return;
  int dst = ei[E + e];
  int p = row_start[dst] + 1 + atomicAdd(&fill[dst], 1);
  csr_src[p] = ei[e];
  pos_map[e] = p;
}

// ea_perm[pos_map[e]] = bf16(concat(ea, loop_attr)[e])   (32 vals per row)
__global__ void k_permute_ea(const float* __restrict__ ea, const float* __restrict__ loop_attr,
                             const int* __restrict__ pos_map, unsigned short* __restrict__ ea_perm,
                             int E, int N){
  int idx = blockIdx.x * 256 + threadIdx.x;   // one float4 per thread
  int e = idx >> 3, q = idx & 7;
  if (e >= E + N) return;
  const float* srcp = (e < E) ? ea + (size_t)e * 32 : loop_attr + (size_t)(e - E) * 32;
  float4 v = ((const float4*)srcp)[q];
  int pos = pos_map[e];
  ushort4 o;
  o.x = f2bf(v.x); o.y = f2bf(v.y); o.z = f2bf(v.z); o.w = f2bf(v.w);
  *(ushort4*)&ea_perm[(size_t)pos * 32 + q * 4] = o;
}

// ---- GEMM: C[M,N] = A[M,K] @ B[K,N] + bias  (M%64==0, N%64==0, K%16==0) ----
template<typename AT, typename OutT>
__global__ __launch_bounds__(256) void k_gemm_bias(const AT* __restrict__ A,
    const float* __restrict__ B, const float* __restrict__ bias, OutT* __restrict__ C,
    int M, int N, int K){
  __shared__ float As[16][64];
  __shared__ float Bs[16][64];
  int t = threadIdx.x;
  int bx = blockIdx.x, by = blockIdx.y;
  int tx = t & 15, ty = t >> 4;
  int la_r = t >> 2;            // 0..63   (m within tile)
  int la_c = (t & 3) << 2;      // 0,4,8,12 (k within tile)
  int lb_r = t >> 4;            // 0..15   (k within tile)
  int lb_c = (t & 15) << 2;     // 0..60   (n within tile)
  const AT* Ap = A + (size_t)(by * 64 + la_r) * K + la_c;
  const float* Bp = B + (size_t)lb_r * N + bx * 64 + lb_c;
  float acc[4][4] = {};
  for (int k0 = 0; k0 < K; k0 += 16){
    float4 a4 = load4(Ap + k0);
    float4 b4 = *(const float4*)(Bp + (size_t)k0 * N);
    __syncthreads();
    As[la_c + 0][la_r] = a4.x;
    As[la_c + 1][la_r] = a4.y;
    As[la_c + 2][la_r] = a4.z;
    As[la_c + 3][la_r] = a4.w;
    *(float4*)&Bs[lb_r][lb_c] = b4;
    __syncthreads();
    #pragma unroll
    for (int kk = 0; kk < 16; ++kk){
      float4 av = *(float4*)&As[kk][ty << 2];
      float4 bv = *(float4*)&Bs[kk][tx << 2];
      acc[0][0] += av.x * bv.x; acc[0][1] += av.x * bv.y; acc[0][2] += av.x * bv.z; acc[0][3] += av.x * bv.w;
      acc[1][0] += av.y * bv.x; acc[1][1] += av.y * bv.y; acc[1][2] += av.y * bv.z; acc[1][3] += av.y * bv.w;
      acc[2][0] += av.z * bv.x; acc[2][1] += av.z * bv.y; acc[2][2] += av.z * bv.z; acc[2][3] += av.z * bv.w;
      acc[3][0] += av.w * bv.x; acc[3][1] += av.w * bv.y; acc[3][2] += av.w * bv.z; acc[3][3] += av.w * bv.w;
    }
  }
  int m0 = by * 64 + (ty << 2);
  int n0 = bx * 64 + (tx << 2);
  float4 bi = *(const float4*)&bias[n0];
  #pragma unroll
  for (int i = 0; i < 4; ++i){
    float4 o = make_float4(acc[i][0] + bi.x, acc[i][1] + bi.y, acc[i][2] + bi.z, acc[i][3] + bi.w);
    store4(&C[(size_t)(m0 + i) * N + n0], o);
  }
}

// ---- EW chunk GEMM: EW[e-rs0, :] = ea_perm[e, 0:32] @ We[32, FO] (bf16 out) -
// for e in [row_start[c0], row_start[c1]); blocks beyond the range early-exit.
__global__ __launch_bounds__(256) void k_gemm_ew(const unsigned short* __restrict__ A,
    const float* __restrict__ B, unsigned short* __restrict__ C,
    const int* __restrict__ row_start, int c0, int c1, int N){
  int rs0 = row_start[c0], rs1 = row_start[c1];
  int e_base = rs0 + blockIdx.y * 64;
  if (e_base >= rs1) return;
  __shared__ float As[32][64];
  __shared__ float Bs[32][64];
  int t = threadIdx.x;
  int bx = blockIdx.x;
  {
    int la_r = t >> 2;             // 0..63 row
    int la_c = (t & 3) << 3;       // 0,8,16,24
    int er = min(e_base + la_r, rs1 - 1);
    const unsigned short* ap = A + (size_t)er * 32 + la_c;
    ushort4 u0 = *(const ushort4*)ap;
    ushort4 u1 = *(const ushort4*)(ap + 4);
    As[la_c + 0][la_r] = bf2f(u0.x); As[la_c + 1][la_r] = bf2f(u0.y);
    As[la_c + 2][la_r] = bf2f(u0.z); As[la_c + 3][la_r] = bf2f(u0.w);
    As[la_c + 4][la_r] = bf2f(u1.x); As[la_c + 5][la_r] = bf2f(u1.y);
    As[la_c + 6][la_r] = bf2f(u1.z); As[la_c + 7][la_r] = bf2f(u1.w);
    int lb_r = t >> 3;             // 0..31 k
    int lb_c = (t & 7) << 3;       // 0..56
    const float* bp = B + (size_t)lb_r * N + bx * 64 + lb_c;
    *(float4*)&Bs[lb_r][lb_c] = *(const float4*)bp;
    *(float4*)&Bs[lb_r][lb_c + 4] = *(const float4*)(bp + 4);
  }
  __syncthreads();
  int tx = t & 15, ty = t >> 4;
  float acc[4][4] = {};
  #pragma unroll
  for (int kk = 0; kk < 32; ++kk){
    float4 av = *(float4*)&As[kk][ty << 2];
    float4 bv = *(float4*)&Bs[kk][tx << 2];
    acc[0][0] += av.x * bv.x; acc[0][1] += av.x * bv.y; acc[0][2] += av.x * bv.z; acc[0][3] += av.x * bv.w;
    acc[1][0] += av.y * bv.x; acc[1][1] += av.y * bv.y; acc[1][2] += av.y * bv.z; acc[1][3] += av.y * bv.w;
    acc[2][0] += av.z * bv.x; acc[2][1] += av.z * bv.y; acc[2][2] += av.z * bv.z; acc[2][3] += av.z * bv.w;
    acc[3][0] += av.w * bv.x; acc[3][1] += av.w * bv.y; acc[3][2] += av.w * bv.z; acc[3][3] += av.w * bv.w;
  }
  int n0 = bx * 64 + (tx << 2);
  #pragma unroll
  for (int i = 0; i < 4; ++i){
    int e = e_base + (ty << 2) + i;
    if (e < rs1){
      ushort4 o;
      o.x = f2bf(acc[i][0]); o.y = f2bf(acc[i][1]);
      o.z = f2bf(acc[i][2]); o.w = f2bf(acc[i][3]);
      *(ushort4*)&C[(size_t)(e - rs0) * N + n0] = o;
    }
  }
}

// ---- fused logit + online-softmax + aggregation (one wave per dst node) ----
// out[n] = relu/act( sum_e alpha_e * xl[src_e] + bc ),
// alpha = softmax_e( sum_j att_j * lrelu(xl[src][j] + xr[n][j] + ew[e][j]) )
// nodes n in [c0, c0 + 4*gridDim.x); EW rows indexed relative to row_start[c0].
template<int CH, typename OutT>   // FO = CH*256
__global__ __launch_bounds__(256) void k_fused_agg(const float* __restrict__ XL,
    const unsigned short* __restrict__ XRb, const unsigned short* __restrict__ EW,
    const int* __restrict__ csr_src, const int* __restrict__ row_start,
    const float* __restrict__ att, const float* __restrict__ bc,
    OutT* __restrict__ out, int c0){
  const int FO = CH * 256;
  int lane = threadIdx.x & 63;
  int wave = threadIdx.x >> 6;
  int n = c0 + blockIdx.x * 4 + wave;
  int rs0 = row_start[c0];
  int rs = row_start[n], re = row_start[n + 1];
  int jj = lane << 2;
  float4 xr[CH], at4[CH], acc[CH];
  #pragma unroll
  for (int c = 0; c < CH; ++c){
    xr[c] = load4(&XRb[(size_t)n * FO + (c << 8) + jj]);
    at4[c] = *(const float4*)&att[(c << 8) + jj];
    acc[c] = make_float4(0.f, 0.f, 0.f, 0.f);
  }
  float m = -1e30f, den = 0.f;
  for (int i = rs; i < re; ++i){
    int s = csr_src[i];
    const float* xp = XL + (size_t)s * FO;
    const unsigned short* ep = EW + (size_t)(i - rs0) * FO;
    float4 xl[CH];
    float tt = 0.f;
    #pragma unroll
    for (int c = 0; c < CH; ++c){
      xl[c] = *(const float4*)&xp[(c << 8) + jj];
      float4 ew = load4(&ep[(c << 8) + jj]);
      float v0 = xl[c].x + xr[c].x + ew.x;
      float v1 = xl[c].y + xr[c].y + ew.y;
      float v2 = xl[c].z + xr[c].z + ew.z;
      float v3 = xl[c].w + xr[c].w + ew.w;
      tt += at4[c].x * lrelu(v0) + at4[c].y * lrelu(v1) + at4[c].z * lrelu(v2) + at4[c].w * lrelu(v3);
    }
    tt = wredsum(tt);
    float mn = fmaxf(m, tt);
    float scale = __expf(m - mn);   // first iter: exp(-huge) = 0
    float f = __expf(tt - mn);
    den = den * scale + f;
    #pragma unroll
    for (int c = 0; c < CH; ++c){
      acc[c].x = acc[c].x * scale + f * xl[c].x;
      acc[c].y = acc[c].y * scale + f * xl[c].y;
      acc[c].z = acc[c].z * scale + f * xl[c].z;
      acc[c].w = acc[c].w * scale + f * xl[c].w;
    }
    m = mn;
  }
  float inv = 1.f / den;
  #pragma unroll
  for (int c = 0; c < CH; ++c){
    float4 b4 = *(const float4*)&bc[(c << 8) + jj];
    float4 o = make_float4(fmaxf(acc[c].x * inv + b4.x, 0.f),
                           fmaxf(acc[c].y * inv + b4.y, 0.f),
                           fmaxf(acc[c].z * inv + b4.z, 0.f),
                           fmaxf(acc[c].w * inv + b4.w, 0.f));
    store4(&out[(size_t)n * FO + (c << 8) + jj], o);
  }
}

// ---- pooling + head --------------------------------------------------------
__global__ void k_pool(const float* __restrict__ H, const int* __restrict__ batch,
                       float* __restrict__ psum, float* __restrict__ pcnt){
  int n = blockIdx.x;
  int j = threadIdx.x;
  int g = batch[n];
  atomicAdd(&psum[g * 256 + j], H[(size_t)n * 256 + j]);
  if (j == 0) atomicAdd(&pcnt[g], 1.f);
}

__global__ void k_fc1(const float* __restrict__ psum, const float* __restrict__ pcnt,
                      const float* __restrict__ w, const float* __restrict__ b,
                      float* __restrict__ z){
  int idx = blockIdx.x * 256 + threadIdx.x;
  if (idx >= 128 * 64) return;
  int g = idx >> 6, j = idx & 63;
  float acc = 0.f;
  for (int k = 0; k < 256; ++k) acc += psum[g * 256 + k] * w[k * 64 + j];
  z[idx] = acc / fmaxf(pcnt[g], 1.f) + b[j];
}

__global__ void k_head(const float* __restrict__ z, const float* __restrict__ bn_g,
                       const float* __restrict__ bn_b, const float* __restrict__ w2,
                       const float* __restrict__ b2, float* __restrict__ out){
  __shared__ float mu_s[64], is_s[64];
  int t = threadIdx.x;  // 128 threads
  if (t < 64){
    float mu = 0.f, m2 = 0.f;
    for (int g = 0; g < 128; ++g){ float v = z[g * 64 + t]; mu += v; m2 += v * v; }
    mu /= 128.f; m2 /= 128.f;
    float var = m2 - mu * mu;
    mu_s[t] = mu;
    is_s[t] = rsqrtf(var + 1e-5f);
  }
  __syncthreads();
  float o = b2[0];
  for (int j = 0; j < 64; ++j){
    float v = (z[t * 64 + j] - mu_s[j]) * is_s[j] * bn_g[j] + bn_b[j];
    o += fmaxf(v, 0.f) * w2[j];
  }
  out[t] = o;
}

extern "C" void kernel_launch(void* const* d_in, const int* in_sizes, int n_in,
                              void* d_out, int out_size, void* d_ws, size_t ws_size,
                              hipStream_t stream){
  const int N = 16384, E = 131072, Eaug = E + N, NG = 128;
  const float* x     = (const float*)d_in[0];
  const int*   ei    = (const int*)  d_in[1];
  const float* ea    = (const float*)d_in[2];
  const int*   batch = (const int*)  d_in[3];
  const float* Wl[3]  = {(const float*)d_in[4],  (const float*)d_in[11], (const float*)d_in[18]};
  const float* bl[3]  = {(const float*)d_in[5],  (const float*)d_in[12], (const float*)d_in[19]};
  const float* Wr[3]  = {(const float*)d_in[6],  (const float*)d_in[13], (const float*)d_in[20]};
  const float* br[3]  = {(const float*)d_in[7],  (const float*)d_in[14], (const float*)d_in[21]};
  const float* We[3]  = {(const float*)d_in[8],  (const float*)d_in[15], (const float*)d_in[22]};
  const float* att[3] = {(const float*)d_in[9],  (const float*)d_in[16], (const float*)d_in[23]};
  const float* bc[3]  = {(const float*)d_in[10], (const float*)d_in[17], (const float*)d_in[24]};
  const float* fc1_w = (const float*)d_in[25];
  const float* fc1_b = (const float*)d_in[26];
  const float* bn_g  = (const float*)d_in[27];
  const float* bn_b  = (const float*)d_in[28];
  const float* fc2_w = (const float*)d_in[29];
  const float* fc2_b = (const float*)d_in[30];
  float* out = (float*)d_out;

  char* wsb = (char*)d_ws;
  size_t off = 0;
  auto alloc = [&](size_t bytes) -> char* {
    char* p = wsb + off;
    off = (off + bytes + 255) & ~(size_t)255;
    return p;
  };
  int*   deg       = (int*)  alloc((size_t)N * 4);
  int*   fill      = (int*)  alloc((size_t)N * 4);
  int*   row_start = (int*)  alloc((size_t)(N + 1) * 4);
  float* loop_attr = (float*)alloc((size_t)N * 32 * 4);
  int*   csr_src   = (int*)  alloc((size_t)Eaug * 4);
  int*   pos_map   = (int*)  alloc((size_t)Eaug * 4);
  unsigned short* ea_perm = (unsigned short*)alloc((size_t)Eaug * 32 * 2);
  float* XL        = (float*)alloc((size_t)N * 1024 * 4);      // 64 MB
  unsigned short* XRb = (unsigned short*)alloc((size_t)N * 1024 * 2); // 32 MB
  float* buf1      = (float*)alloc((size_t)N * 512 * 4);       // 32 MB: L1 out fp32 / L3 out fp32(256)
  unsigned short* buf2b = (unsigned short*)alloc((size_t)N * 1024 * 2); // 32 MB: L2 out bf16
  unsigned short* EWbuf = (unsigned short*)alloc((size_t)32 << 20);    // 32 MB EW chunk ring
  float* psum      = (float*)alloc((size_t)NG * 256 * 4);
  float* pcnt      = (float*)alloc((size_t)NG * 4);
  float* zbuf      = (float*)alloc((size_t)NG * 64 * 4);
  // total ~204.5 MiB == round-3's proven footprint

  hipMemsetAsync(deg, 0, (size_t)N * 4, stream);
  hipMemsetAsync(fill, 0, (size_t)N * 4, stream);
  hipMemsetAsync(loop_attr, 0, (size_t)N * 32 * 4, stream);
  hipMemsetAsync(psum, 0, (size_t)NG * 256 * 4, stream);
  hipMemsetAsync(pcnt, 0, (size_t)NG * 4, stream);

  k_deg_attr<<<(E * 32) / 256, 256, 0, stream>>>(ei, ea, deg, loop_attr, E);
  k_loop_div<<<(N * 32) / 256, 256, 0, stream>>>(loop_attr, deg, N);
  k_scan<<<1, 256, 0, stream>>>(deg, row_start, N);
  k_csr_self<<<N / 256, 256, 0, stream>>>(row_start, csr_src, pos_map, N, E);
  k_csr_fill<<<E / 256, 256, 0, stream>>>(ei, row_start, fill, csr_src, pos_map, E);
  k_permute_ea<<<(Eaug * 8) / 256, 256, 0, stream>>>(ea, loop_attr, pos_map, ea_perm, E, N);

  const size_t EWCAP = (size_t)32 << 20;

  // ---- layer 1: FI=256, FO=512, in x (fp32), out buf1 (fp32) ----
  {
    const int FI = 256, FO = 512;
    dim3 gg(FO / 64, N / 64);
    k_gemm_bias<float, float><<<gg, 256, 0, stream>>>(x, Wl[0], bl[0], XL, N, FO, FI);
    k_gemm_bias<float, unsigned short><<<gg, 256, 0, stream>>>(x, Wr[0], br[0], XRb, N, FO, FI);
    int budget = (int)(EWCAP / (FO * 2));          // 32768 edges
    int nchunks = 8, npc = N / 8;                  // ~18.4K expected edges/chunk
    for (int c = 0; c < nchunks; ++c){
      dim3 eg(FO / 64, budget / 64);
      k_gemm_ew<<<eg, 256, 0, stream>>>(ea_perm, We[0], EWbuf, row_start, c * npc, (c + 1) * npc, FO);
      k_fused_agg<2, float><<<npc / 4, 256, 0, stream>>>(XL, XRb, EWbuf, csr_src, row_start, att[0], bc[0], buf1, c * npc);
    }
  }
  // ---- layer 2: FI=512, FO=1024, in buf1 (fp32), out buf2b (bf16) ----
  {
    const int FI = 512, FO = 1024;
    dim3 gg(FO / 64, N / 64);
    k_gemm_bias<float, float><<<gg, 256, 0, stream>>>(buf1, Wl[1], bl[1], XL, N, FO, FI);
    k_gemm_bias<float, unsigned short><<<gg, 256, 0, stream>>>(buf1, Wr[1], br[1], XRb, N, FO, FI);
    int budget = (int)(EWCAP / (FO * 2));          // 16384 edges
    int nchunks = 16, npc = N / 16;                // ~9.2K expected edges/chunk
    for (int c = 0; c < nchunks; ++c){
      dim3 eg(FO / 64, budget / 64);
      k_gemm_ew<<<eg, 256, 0, stream>>>(ea_perm, We[1], EWbuf, row_start, c * npc, (c + 1) * npc, FO);
      k_fused_agg<4, unsigned short><<<npc / 4, 256, 0, stream>>>(XL, XRb, EWbuf, csr_src, row_start, att[1], bc[1], buf2b, c * npc);
    }
  }
  // ---- layer 3: FI=1024, FO=256, in buf2b (bf16), out buf1 (fp32) ----
  {
    const int FI = 1024, FO = 256;
    dim3 gg(FO / 64, N / 64);
    k_gemm_bias<unsigned short, float><<<gg, 256, 0, stream>>>(buf2b, Wl[2], bl[2], XL, N, FO, FI);
    k_gemm_bias<unsigned short, unsigned short><<<gg, 256, 0, stream>>>(buf2b, Wr[2], br[2], XRb, N, FO, FI);
    int budget = (int)(EWCAP / (FO * 2));          // 65536 edges
    int nchunks = 4, npc = N / 4;                  // ~36.9K expected edges/chunk
    for (int c = 0; c < nchunks; ++c){
      dim3 eg(FO / 64, budget / 64);
      k_gemm_ew<<<eg, 256, 0, stream>>>(ea_perm, We[2], EWbuf, row_start, c * npc, (c + 1) * npc, FO);
      k_fused_agg<1, float><<<npc / 4, 256, 0, stream>>>(XL, XRb, EWbuf, csr_src, row_start, att[2], bc[2], buf1, c * npc);
    }
  }

  k_pool<<<N, 256, 0, stream>>>(buf1, batch, psum, pcnt);
  k_fc1<<<32, 256, 0, stream>>>(psum, pcnt, fc1_w, fc1_b, zbuf);
  k_head<<<1, 128, 0, stream>>>(zbuf, bn_g, bn_b, fc2_w, fc2_b, out);
}

// Round 5
// 1301.913 us; speedup vs baseline: 9.5003x; 1.9032x over previous
//
#include <hip/hip_runtime.h>
#include <hip/hip_bf16.h>
#include <math.h>

#define NEG_SLOPE 0.2f

typedef short bf16x8 __attribute__((ext_vector_type(8)));
typedef float f32x4 __attribute__((ext_vector_type(4)));

__device__ __forceinline__ float wredsum(float v){
  #pragma unroll
  for (int o = 32; o; o >>= 1) v += __shfl_xor(v, o, 64);
  return v;
}
__device__ __forceinline__ float lrelu(float x){ return x >= 0.f ? x : NEG_SLOPE * x; }
__device__ __forceinline__ unsigned short f2bf(float f){
  __hip_bfloat16 h = __float2bfloat16(f);
  return *(unsigned short*)&h;
}
__device__ __forceinline__ float bf2f(unsigned short u){
  return __uint_as_float((unsigned)u << 16);
}

__device__ __forceinline__ float4 load4(const float* p){ return *(const float4*)p; }
__device__ __forceinline__ float4 load4(const unsigned short* p){
  ushort4 u = *(const ushort4*)p;
  return make_float4(bf2f(u.x), bf2f(u.y), bf2f(u.z), bf2f(u.w));
}
__device__ __forceinline__ void store4(float* p, float4 v){ *(float4*)p = v; }
__device__ __forceinline__ void store4(unsigned short* p, float4 v){
  ushort4 o; o.x = f2bf(v.x); o.y = f2bf(v.y); o.z = f2bf(v.z); o.w = f2bf(v.w);
  *(ushort4*)p = o;
}

// ---- CSR construction ------------------------------------------------------
__global__ void k_deg_attr(const int* __restrict__ ei, const float* __restrict__ ea,
                           int* __restrict__ deg, float* __restrict__ loop_attr, int E){
  int idx = blockIdx.x * 256 + threadIdx.x;
  int e = idx >> 5, k = idx & 31;
  if (e >= E) return;
  int dst = ei[E + e];
  atomicAdd(&loop_attr[dst * 32 + k], ea[(size_t)e * 32 + k]);
  if (k == 0) atomicAdd(&deg[dst], 1);
}

__global__ void k_loop_div(float* __restrict__ loop_attr, const int* __restrict__ deg, int N){
  int idx = blockIdx.x * 256 + threadIdx.x;
  if (idx >= N * 32) return;
  float d = (float)max(deg[idx >> 5], 1);
  loop_attr[idx] /= d;
}

__global__ void k_scan(const int* __restrict__ deg, int* __restrict__ row_start, int N){
  __shared__ int s[256];
  int t = threadIdx.x;
  int base = t * 64;
  int sum = 0;
  for (int i = 0; i < 64; ++i) sum += deg[base + i] + 1;
  s[t] = sum;
  __syncthreads();
  for (int off = 1; off < 256; off <<= 1){
    int v = (t >= off) ? s[t - off] : 0;
    __syncthreads();
    s[t] += v;
    __syncthreads();
  }
  int run = s[t] - sum;   // exclusive
  for (int i = 0; i < 64; ++i){ row_start[base + i] = run; run += deg[base + i] + 1; }
  if (t == 255) row_start[N] = run;
}

__global__ void k_csr_self(const int* __restrict__ row_start, int* __restrict__ csr_src,
                           int* __restrict__ pos_map, int N, int E){
  int n = blockIdx.x * 256 + threadIdx.x;
  if (n >= N) return;
  int p = row_start[n];
  csr_src[p] = n;
  pos_map[E + n] = p;
}

__global__ void k_csr_fill(const int* __restrict__ ei, const int* __restrict__ row_start,
                           int* __restrict__ fill, int* __restrict__ csr_src,
                           int* __restrict__ pos_map, int E){
  int e = blockIdx.x * 256 + threadIdx.x;
  if (e >= E) return;
  int dst = ei[E + e];
  int p = row_start[dst] + 1 + atomicAdd(&fill[dst], 1);
  csr_src[p] = ei[e];
  pos_map[e] = p;
}

__global__ void k_permute_ea(const float* __restrict__ ea, const float* __restrict__ loop_attr,
                             const int* __restrict__ pos_map, unsigned short* __restrict__ ea_perm,
                             int E, int N){
  int idx = blockIdx.x * 256 + threadIdx.x;
  int e = idx >> 3, q = idx & 7;
  if (e >= E + N) return;
  const float* srcp = (e < E) ? ea + (size_t)e * 32 : loop_attr + (size_t)(e - E) * 32;
  float4 v = ((const float4*)srcp)[q];
  int pos = pos_map[e];
  ushort4 o;
  o.x = f2bf(v.x); o.y = f2bf(v.y); o.z = f2bf(v.z); o.w = f2bf(v.w);
  *(ushort4*)&ea_perm[(size_t)pos * 32 + q * 4] = o;
}

// ---- dtype prep ------------------------------------------------------------
__global__ void k_cvt_bf16(const float* __restrict__ in, unsigned short* __restrict__ out, int n4){
  int idx = blockIdx.x * 256 + threadIdx.x;
  if (idx >= n4) return;
  float4 v = *(const float4*)&in[idx * 4];
  store4(&out[idx * 4], v);
}

// W[K,N] fp32 -> Wt[N,K] bf16, K,N multiples of 64
__global__ __launch_bounds__(256) void k_transpose_bf16(const float* __restrict__ W,
    unsigned short* __restrict__ Wt, int K, int N){
  __shared__ float tile[64][65];
  int n0 = blockIdx.x * 64, k0 = blockIdx.y * 64;
  int col = threadIdx.x & 63, rq = threadIdx.x >> 6;
  #pragma unroll
  for (int i = 0; i < 16; ++i){
    int r = rq * 16 + i;
    tile[r][col] = W[(size_t)(k0 + r) * N + n0 + col];
  }
  __syncthreads();
  #pragma unroll
  for (int i = 0; i < 16; ++i){
    int r = rq * 16 + i;
    Wt[(size_t)(n0 + r) * K + k0 + col] = f2bf(tile[col][r]);
  }
}

// We[32,FO] fp32 -> WeT[FO,32] bf16 (small, naive)
__global__ void k_transpose_we(const float* __restrict__ We, unsigned short* __restrict__ WeT, int FO){
  int idx = blockIdx.x * 256 + threadIdx.x;
  if (idx >= 32 * FO) return;
  int k = idx / FO, n = idx % FO;
  WeT[n * 32 + k] = f2bf(We[idx]);
}

// ---- bf16 MFMA GEMM: C[M,N] = A[M,K] @ Bt[N,K]^T + bias --------------------
// A, Bt bf16 row-major (K contiguous). M%128==0, N%128==0, K%32==0.
template<typename OutT>
__global__ void k_mfma_gemm(const unsigned short* __restrict__ A,
    const unsigned short* __restrict__ Bt, const float* __restrict__ bias,
    OutT* __restrict__ C, int M, int N, int K){
  __shared__ unsigned short As[128 * 40];
  __shared__ unsigned short Bs[128 * 40];
  int t = threadIdx.x;
  int bx = blockIdx.x, by = blockIdx.y;
  int lane = t & 63, w = t >> 6;
  int wm = (w & 1) * 64, wn = (w >> 1) * 64;
  int lo = lane & 15, hi = lane >> 4;
  int srow = t >> 2, skq = (t & 3) * 8;      // staging: row, k-offset
  f32x4 acc[4][4] = {};
  for (int k0 = 0; k0 < K; k0 += 32){
    // stage A[128][32], Bt[128][32] (two 64-row passes each)
    #pragma unroll
    for (int p = 0; p < 2; ++p){
      int r = p * 64 + srow;
      *(float4*)&As[r * 40 + skq] = *(const float4*)&A[(size_t)(by * 128 + r) * K + k0 + skq];
      *(float4*)&Bs[r * 40 + skq] = *(const float4*)&Bt[(size_t)(bx * 128 + r) * K + k0 + skq];
    }
    __syncthreads();
    bf16x8 af[4], bf[4];
    #pragma unroll
    for (int i = 0; i < 4; ++i){
      af[i] = *(const bf16x8*)&As[(wm + i * 16 + lo) * 40 + hi * 8];
      bf[i] = *(const bf16x8*)&Bs[(wn + i * 16 + lo) * 40 + hi * 8];
    }
    #pragma unroll
    for (int mi = 0; mi < 4; ++mi)
      #pragma unroll
      for (int ni = 0; ni < 4; ++ni)
        acc[mi][ni] = __builtin_amdgcn_mfma_f32_16x16x32_bf16(af[mi], bf[ni], acc[mi][ni], 0, 0, 0);
    __syncthreads();
  }
  // epilogue: C row = (lane>>4)*4 + reg, col = lane&15
  #pragma unroll
  for (int ni = 0; ni < 4; ++ni){
    int col = bx * 128 + wn + ni * 16 + lo;
    float bv = bias ? bias[col] : 0.f;
    #pragma unroll
    for (int mi = 0; mi < 4; ++mi){
      int row0 = by * 128 + wm + mi * 16 + hi * 4;
      #pragma unroll
      for (int r = 0; r < 4; ++r){
        float v = acc[mi][ni][r] + bv;
        OutT* p = &C[(size_t)(row0 + r) * N + col];
        if (sizeof(OutT) == 4) *(float*)p = v; else *(unsigned short*)p = f2bf(v);
      }
    }
  }
}

// ---- EW MFMA GEMM (K=32, no LDS): EW[e-rs0,:] = ea_perm[e,:] @ WeT[n,:]^T --
__global__ void k_mfma_ew(const unsigned short* __restrict__ Ap,
    const unsigned short* __restrict__ WeT, unsigned short* __restrict__ EW,
    const int* __restrict__ row_start, int c0, int c1, int N){
  int rs0 = row_start[c0], rs1 = row_start[c1];
  int e_base = rs0 + blockIdx.y * 128;
  if (e_base >= rs1) return;
  int t = threadIdx.x;
  int bx = blockIdx.x;
  int lane = t & 63, w = t >> 6;
  int wm = (w & 1) * 64, wn = (w >> 1) * 64;
  int lo = lane & 15, hi = lane >> 4;
  bf16x8 af[4], bf[4];
  #pragma unroll
  for (int i = 0; i < 4; ++i){
    int e = min(e_base + wm + i * 16 + lo, rs1 - 1);
    af[i] = *(const bf16x8*)&Ap[(size_t)e * 32 + hi * 8];
    int n = bx * 128 + wn + i * 16 + lo;
    bf[i] = *(const bf16x8*)&WeT[(size_t)n * 32 + hi * 8];
  }
  f32x4 acc[4][4] = {};
  #pragma unroll
  for (int mi = 0; mi < 4; ++mi)
    #pragma unroll
    for (int ni = 0; ni < 4; ++ni)
      acc[mi][ni] = __builtin_amdgcn_mfma_f32_16x16x32_bf16(af[mi], bf[ni], acc[mi][ni], 0, 0, 0);
  #pragma unroll
  for (int mi = 0; mi < 4; ++mi){
    int e0 = e_base + wm + mi * 16 + hi * 4;
    #pragma unroll
    for (int r = 0; r < 4; ++r){
      int e = e0 + r;
      if (e < rs1){
        #pragma unroll
        for (int ni = 0; ni < 4; ++ni){
          int col = bx * 128 + wn + ni * 16 + lo;
          EW[(size_t)(e - rs0) * N + col] = f2bf(acc[mi][ni][r]);
        }
      }
    }
  }
}

// ---- fused logit + online-softmax + aggregation (one wave per dst node) ----
template<int CH, typename OutT>   // FO = CH*256
__global__ __launch_bounds__(256) void k_fused_agg(const float* __restrict__ XL,
    const unsigned short* __restrict__ XRb, const unsigned short* __restrict__ EW,
    const int* __restrict__ csr_src, const int* __restrict__ row_start,
    const float* __restrict__ att, const float* __restrict__ bc,
    OutT* __restrict__ out, int c0){
  const int FO = CH * 256;
  int lane = threadIdx.x & 63;
  int wave = threadIdx.x >> 6;
  int n = c0 + blockIdx.x * 4 + wave;
  int rs0 = row_start[c0];
  int rs = row_start[n], re = row_start[n + 1];
  int jj = lane << 2;
  float4 xr[CH], at4[CH], acc[CH];
  #pragma unroll
  for (int c = 0; c < CH; ++c){
    xr[c] = load4(&XRb[(size_t)n * FO + (c << 8) + jj]);
    at4[c] = *(const float4*)&att[(c << 8) + jj];
    acc[c] = make_float4(0.f, 0.f, 0.f, 0.f);
  }
  float m = -1e30f, den = 0.f;
  for (int i = rs; i < re; ++i){
    int s = csr_src[i];
    const float* xp = XL + (size_t)s * FO;
    const unsigned short* ep = EW + (size_t)(i - rs0) * FO;
    float4 xl[CH];
    float tt = 0.f;
    #pragma unroll
    for (int c = 0; c < CH; ++c){
      xl[c] = *(const float4*)&xp[(c << 8) + jj];
      float4 ew = load4(&ep[(c << 8) + jj]);
      float v0 = xl[c].x + xr[c].x + ew.x;
      float v1 = xl[c].y + xr[c].y + ew.y;
      float v2 = xl[c].z + xr[c].z + ew.z;
      float v3 = xl[c].w + xr[c].w + ew.w;
      tt += at4[c].x * lrelu(v0) + at4[c].y * lrelu(v1) + at4[c].z * lrelu(v2) + at4[c].w * lrelu(v3);
    }
    tt = wredsum(tt);
    float mn = fmaxf(m, tt);
    float scale = __expf(m - mn);
    float f = __expf(tt - mn);
    den = den * scale + f;
    #pragma unroll
    for (int c = 0; c < CH; ++c){
      acc[c].x = acc[c].x * scale + f * xl[c].x;
      acc[c].y = acc[c].y * scale + f * xl[c].y;
      acc[c].z = acc[c].z * scale + f * xl[c].z;
      acc[c].w = acc[c].w * scale + f * xl[c].w;
    }
    m = mn;
  }
  float inv = 1.f / den;
  #pragma unroll
  for (int c = 0; c < CH; ++c){
    float4 b4 = *(const float4*)&bc[(c << 8) + jj];
    float4 o = make_float4(fmaxf(acc[c].x * inv + b4.x, 0.f),
                           fmaxf(acc[c].y * inv + b4.y, 0.f),
                           fmaxf(acc[c].z * inv + b4.z, 0.f),
                           fmaxf(acc[c].w * inv + b4.w, 0.f));
    store4(&out[(size_t)n * FO + (c << 8) + jj], o);
  }
}

// ---- pooling + head --------------------------------------------------------
__global__ void k_pool(const float* __restrict__ H, const int* __restrict__ batch,
                       float* __restrict__ psum, float* __restrict__ pcnt){
  int n = blockIdx.x;
  int j = threadIdx.x;
  int g = batch[n];
  atomicAdd(&psum[g * 256 + j], H[(size_t)n * 256 + j]);
  if (j == 0) atomicAdd(&pcnt[g], 1.f);
}

__global__ void k_fc1(const float* __restrict__ psum, const float* __restrict__ pcnt,
                      const float* __restrict__ w, const float* __restrict__ b,
                      float* __restrict__ z){
  int idx = blockIdx.x * 256 + threadIdx.x;
  if (idx >= 128 * 64) return;
  int g = idx >> 6, j = idx & 63;
  float acc = 0.f;
  for (int k = 0; k < 256; ++k) acc += psum[g * 256 + k] * w[k * 64 + j];
  z[idx] = acc / fmaxf(pcnt[g], 1.f) + b[j];
}

__global__ void k_head(const float* __restrict__ z, const float* __restrict__ bn_g,
                       const float* __restrict__ bn_b, const float* __restrict__ w2,
                       const float* __restrict__ b2, float* __restrict__ out){
  __shared__ float mu_s[64], is_s[64];
  int t = threadIdx.x;  // 128 threads
  if (t < 64){
    float mu = 0.f, m2 = 0.f;
    for (int g = 0; g < 128; ++g){ float v = z[g * 64 + t]; mu += v; m2 += v * v; }
    mu /= 128.f; m2 /= 128.f;
    float var = m2 - mu * mu;
    mu_s[t] = mu;
    is_s[t] = rsqrtf(var + 1e-5f);
  }
  __syncthreads();
  float o = b2[0];
  for (int j = 0; j < 64; ++j){
    float v = (z[t * 64 + j] - mu_s[j]) * is_s[j] * bn_g[j] + bn_b[j];
    o += fmaxf(v, 0.f) * w2[j];
  }
  out[t] = o;
}

extern "C" void kernel_launch(void* const* d_in, const int* in_sizes, int n_in,
                              void* d_out, int out_size, void* d_ws, size_t ws_size,
                              hipStream_t stream){
  const int N = 16384, E = 131072, Eaug = E + N, NG = 128;
  const float* x     = (const float*)d_in[0];
  const int*   ei    = (const int*)  d_in[1];
  const float* ea    = (const float*)d_in[2];
  const int*   batch = (const int*)  d_in[3];
  const float* Wl[3]  = {(const float*)d_in[4],  (const float*)d_in[11], (const float*)d_in[18]};
  const float* bl[3]  = {(const float*)d_in[5],  (const float*)d_in[12], (const float*)d_in[19]};
  const float* Wr[3]  = {(const float*)d_in[6],  (const float*)d_in[13], (const float*)d_in[20]};
  const float* br[3]  = {(const float*)d_in[7],  (const float*)d_in[14], (const float*)d_in[21]};
  const float* We[3]  = {(const float*)d_in[8],  (const float*)d_in[15], (const float*)d_in[22]};
  const float* att[3] = {(const float*)d_in[9],  (const float*)d_in[16], (const float*)d_in[23]};
  const float* bc[3]  = {(const float*)d_in[10], (const float*)d_in[17], (const float*)d_in[24]};
  const float* fc1_w = (const float*)d_in[25];
  const float* fc1_b = (const float*)d_in[26];
  const float* bn_g  = (const float*)d_in[27];
  const float* bn_b  = (const float*)d_in[28];
  const float* fc2_w = (const float*)d_in[29];
  const float* fc2_b = (const float*)d_in[30];
  float* out = (float*)d_out;

  char* wsb = (char*)d_ws;
  size_t off = 0;
  auto alloc = [&](size_t bytes) -> char* {
    char* p = wsb + off;
    off = (off + bytes + 255) & ~(size_t)255;
    return p;
  };
  int*   deg       = (int*)  alloc((size_t)N * 4);
  int*   fill      = (int*)  alloc((size_t)N * 4);
  int*   row_start = (int*)  alloc((size_t)(N + 1) * 4);
  float* loop_attr = (float*)alloc((size_t)N * 32 * 4);
  int*   csr_src   = (int*)  alloc((size_t)Eaug * 4);
  int*   pos_map   = (int*)  alloc((size_t)Eaug * 4);
  unsigned short* ea_perm = (unsigned short*)alloc((size_t)Eaug * 32 * 2);
  float* XL        = (float*)alloc((size_t)N * 1024 * 4);            // 64 MB
  unsigned short* XRb  = (unsigned short*)alloc((size_t)N * 1024 * 2); // 32 MB
  unsigned short* bufA = (unsigned short*)alloc((size_t)N * 1024 * 2); // 32 MB: Xb / L2-out
  unsigned short* bufB = (unsigned short*)alloc((size_t)N * 512 * 4);  // 32 MB: L1-out bf16 / L3-out fp32
  unsigned short* EWbuf = (unsigned short*)alloc((size_t)32 << 20);    // 32 MB EW ring
  unsigned short* WtL  = (unsigned short*)alloc((size_t)1024 * 1024 * 2);
  unsigned short* WtR  = (unsigned short*)alloc((size_t)1024 * 1024 * 2);
  unsigned short* WeT  = (unsigned short*)alloc((size_t)1024 * 32 * 2);
  float* psum      = (float*)alloc((size_t)NG * 256 * 4);
  float* pcnt      = (float*)alloc((size_t)NG * 4);
  float* zbuf      = (float*)alloc((size_t)NG * 64 * 4);
  // ~200 MiB total (round-4's 204.5 MiB footprint passed)

  hipMemsetAsync(deg, 0, (size_t)N * 4, stream);
  hipMemsetAsync(fill, 0, (size_t)N * 4, stream);
  hipMemsetAsync(loop_attr, 0, (size_t)N * 32 * 4, stream);
  hipMemsetAsync(psum, 0, (size_t)NG * 256 * 4, stream);
  hipMemsetAsync(pcnt, 0, (size_t)NG * 4, stream);

  k_deg_attr<<<(E * 32) / 256, 256, 0, stream>>>(ei, ea, deg, loop_attr, E);
  k_loop_div<<<(N * 32) / 256, 256, 0, stream>>>(loop_attr, deg, N);
  k_scan<<<1, 256, 0, stream>>>(deg, row_start, N);
  k_csr_self<<<N / 256, 256, 0, stream>>>(row_start, csr_src, pos_map, N, E);
  k_csr_fill<<<E / 256, 256, 0, stream>>>(ei, row_start, fill, csr_src, pos_map, E);
  k_permute_ea<<<(Eaug * 8) / 256, 256, 0, stream>>>(ea, loop_attr, pos_map, ea_perm, E, N);
  k_cvt_bf16<<<(N * 256 / 4) / 256, 256, 0, stream>>>(x, bufA, N * 256 / 4);

  const size_t EWCAP = (size_t)32 << 20;
  const int fin[3] = {256, 512, 1024};
  const int fo[3]  = {512, 1024, 256};
  const int nch[3] = {8, 16, 4};
  // A-operand (bf16) per layer; agg output target per layer
  const unsigned short* Ain[3] = {bufA, bufB, bufA};

  for (int L = 0; L < 3; ++L){
    int FI = fin[L], FO = fo[L];
    // weight prep
    k_transpose_bf16<<<dim3(FO / 64, FI / 64), 256, 0, stream>>>(Wl[L], WtL, FI, FO);
    k_transpose_bf16<<<dim3(FO / 64, FI / 64), 256, 0, stream>>>(Wr[L], WtR, FI, FO);
    k_transpose_we<<<(32 * FO + 255) / 256, 256, 0, stream>>>(We[L], WeT, FO);
    // projections (MFMA)
    dim3 gg(FO / 128, N / 128);
    k_mfma_gemm<float><<<gg, 256, 0, stream>>>(Ain[L], WtL, bl[L], XL, N, FO, FI);
    k_mfma_gemm<unsigned short><<<gg, 256, 0, stream>>>(Ain[L], WtR, br[L], XRb, N, FO, FI);
    // chunked EW + fused agg
    int budget = (int)(EWCAP / (FO * 2));
    int nchunks = nch[L], npc = N / nchunks;
    for (int c = 0; c < nchunks; ++c){
      dim3 eg(FO / 128, budget / 128);
      k_mfma_ew<<<eg, 256, 0, stream>>>(ea_perm, WeT, EWbuf, row_start, c * npc, (c + 1) * npc, FO);
      if (FO == 512)
        k_fused_agg<2, unsigned short><<<npc / 4, 256, 0, stream>>>(XL, XRb, EWbuf, csr_src, row_start, att[L], bc[L], bufB, c * npc);
      else if (FO == 1024)
        k_fused_agg<4, unsigned short><<<npc / 4, 256, 0, stream>>>(XL, XRb, EWbuf, csr_src, row_start, att[L], bc[L], bufA, c * npc);
      else
        k_fused_agg<1, float><<<npc / 4, 256, 0, stream>>>(XL, XRb, EWbuf, csr_src, row_start, att[L], bc[L], (float*)bufB, c * npc);
    }
  }

  k_pool<<<N, 256, 0, stream>>>((const float*)bufB, batch, psum, pcnt);
  k_fc1<<<32, 256, 0, stream>>>(psum, pcnt, fc1_w, fc1_b, zbuf);
  k_head<<<1, 128, 0, stream>>>(zbuf, bn_g, bn_b, fc2_w, fc2_b, out);
}

// Round 6
// 928.392 us; speedup vs baseline: 13.3226x; 1.4023x over previous
//
#include <hip/hip_runtime.h>
#include <hip/hip_bf16.h>
#include <math.h>

#define NEG_SLOPE 0.2f

typedef short bf16x8 __attribute__((ext_vector_type(8)));
typedef float f32x4 __attribute__((ext_vector_type(4)));

__device__ __forceinline__ float wredsum(float v){
  #pragma unroll
  for (int o = 32; o; o >>= 1) v += __shfl_xor(v, o, 64);
  return v;
}
__device__ __forceinline__ float lrelu(float x){ return x >= 0.f ? x : NEG_SLOPE * x; }
__device__ __forceinline__ unsigned short f2bf(float f){
  __hip_bfloat16 h = __float2bfloat16(f);
  return *(unsigned short*)&h;
}
__device__ __forceinline__ float bf2f(unsigned short u){
  return __uint_as_float((unsigned)u << 16);
}

__device__ __forceinline__ float4 load4(const float* p){ return *(const float4*)p; }
__device__ __forceinline__ float4 load4(const unsigned short* p){
  ushort4 u = *(const ushort4*)p;
  return make_float4(bf2f(u.x), bf2f(u.y), bf2f(u.z), bf2f(u.w));
}
__device__ __forceinline__ void store4(float* p, float4 v){ *(float4*)p = v; }
__device__ __forceinline__ void store4(unsigned short* p, float4 v){
  ushort4 o; o.x = f2bf(v.x); o.y = f2bf(v.y); o.z = f2bf(v.z); o.w = f2bf(v.w);
  *(ushort4*)p = o;
}

// ---- CSR construction ------------------------------------------------------
__global__ void k_deg(const int* __restrict__ ei, int* __restrict__ deg, int E){
  int e = blockIdx.x * 256 + threadIdx.x;
  if (e >= E) return;
  atomicAdd(&deg[ei[E + e]], 1);
}

// row width = deg[n] + 1 (self loop).  N = 16384 = 256 * 64, single block scan.
__global__ void k_scan(const int* __restrict__ deg, int* __restrict__ row_start, int N){
  __shared__ int s[256];
  int t = threadIdx.x;
  int base = t * 64;
  int sum = 0;
  for (int i = 0; i < 64; ++i) sum += deg[base + i] + 1;
  s[t] = sum;
  __syncthreads();
  for (int off = 1; off < 256; off <<= 1){
    int v = (t >= off) ? s[t - off] : 0;
    __syncthreads();
    s[t] += v;
    __syncthreads();
  }
  int run = s[t] - sum;   // exclusive
  for (int i = 0; i < 64; ++i){ row_start[base + i] = run; run += deg[base + i] + 1; }
  if (t == 255) row_start[N] = run;
}

__global__ void k_csr_self(const int* __restrict__ row_start, int* __restrict__ csr_src,
                           int* __restrict__ csr_eid, int N, int E){
  int n = blockIdx.x * 256 + threadIdx.x;
  if (n >= N) return;
  int p = row_start[n];
  csr_src[p] = n;          // self loop in slot 0
  csr_eid[p] = E;          // sentinel: not a real edge
}

__global__ void k_csr_fill(const int* __restrict__ ei, const int* __restrict__ row_start,
                           int* __restrict__ fill, int* __restrict__ csr_src,
                           int* __restrict__ csr_eid, int E){
  int e = blockIdx.x * 256 + threadIdx.x;
  if (e >= E) return;
  int dst = ei[E + e];
  int p = row_start[dst] + 1 + atomicAdd(&fill[dst], 1);
  csr_src[p] = ei[e];
  csr_eid[p] = e;
}

// self-loop attr = mean of incoming ea rows; written straight into ea_perm slot 0.
// half-wave (32 lanes) per node, lane k owns feature k.
__global__ void k_loop_attr(const float* __restrict__ ea, const int* __restrict__ csr_eid,
                            const int* __restrict__ row_start,
                            unsigned short* __restrict__ ea_perm, int N){
  int t = threadIdx.x;
  int half = t >> 5, k = t & 31;
  int n = blockIdx.x * 8 + half;
  if (n >= N) return;
  int rs = row_start[n], re = row_start[n + 1];
  float sum = 0.f;
  for (int i = rs + 1; i < re; ++i){
    int e = csr_eid[i];
    sum += ea[(size_t)e * 32 + k];
  }
  float d = (float)max(re - rs - 1, 1);
  ea_perm[(size_t)rs * 32 + k] = f2bf(sum / d);
}

// non-self rows: ea_perm[p] = bf16(ea[csr_eid[p]])
__global__ void k_permute_pos(const float* __restrict__ ea, const int* __restrict__ csr_eid,
                              unsigned short* __restrict__ ea_perm, int Eaug, int E){
  int idx = blockIdx.x * 256 + threadIdx.x;
  int p = idx >> 3, q = idx & 7;
  if (p >= Eaug) return;
  int e = csr_eid[p];
  if (e >= E) return;   // self slot, handled by k_loop_attr
  float4 v = ((const float4*)(ea + (size_t)e * 32))[q];
  ushort4 o;
  o.x = f2bf(v.x); o.y = f2bf(v.y); o.z = f2bf(v.z); o.w = f2bf(v.w);
  *(ushort4*)&ea_perm[(size_t)p * 32 + q * 4] = o;
}

// ---- dtype prep ------------------------------------------------------------
__global__ void k_cvt_bf16(const float* __restrict__ in, unsigned short* __restrict__ out, int n4){
  int idx = blockIdx.x * 256 + threadIdx.x;
  if (idx >= n4) return;
  float4 v = *(const float4*)&in[idx * 4];
  store4(&out[idx * 4], v);
}

// W[K,N] fp32 -> Wt[N,K] bf16, K,N multiples of 64
__global__ __launch_bounds__(256) void k_transpose_bf16(const float* __restrict__ W,
    unsigned short* __restrict__ Wt, int K, int N){
  __shared__ float tile[64][65];
  int n0 = blockIdx.x * 64, k0 = blockIdx.y * 64;
  int col = threadIdx.x & 63, rq = threadIdx.x >> 6;
  #pragma unroll
  for (int i = 0; i < 16; ++i){
    int r = rq * 16 + i;
    tile[r][col] = W[(size_t)(k0 + r) * N + n0 + col];
  }
  __syncthreads();
  #pragma unroll
  for (int i = 0; i < 16; ++i){
    int r = rq * 16 + i;
    Wt[(size_t)(n0 + r) * K + k0 + col] = f2bf(tile[col][r]);
  }
}

__global__ void k_transpose_we(const float* __restrict__ We, unsigned short* __restrict__ WeT, int FO){
  int idx = blockIdx.x * 256 + threadIdx.x;
  if (idx >= 32 * FO) return;
  int k = idx / FO, n = idx % FO;
  WeT[n * 32 + k] = f2bf(We[idx]);
}

// ---- bf16 MFMA GEMM: C[M,N] = A[M,K] @ Bt[N,K]^T + bias --------------------
template<typename OutT>
__global__ void k_mfma_gemm(const unsigned short* __restrict__ A,
    const unsigned short* __restrict__ Bt, const float* __restrict__ bias,
    OutT* __restrict__ C, int M, int N, int K){
  __shared__ unsigned short As[128 * 40];
  __shared__ unsigned short Bs[128 * 40];
  int t = threadIdx.x;
  int bx = blockIdx.x, by = blockIdx.y;
  int lane = t & 63, w = t >> 6;
  int wm = (w & 1) * 64, wn = (w >> 1) * 64;
  int lo = lane & 15, hi = lane >> 4;
  int srow = t >> 2, skq = (t & 3) * 8;
  f32x4 acc[4][4] = {};
  for (int k0 = 0; k0 < K; k0 += 32){
    #pragma unroll
    for (int p = 0; p < 2; ++p){
      int r = p * 64 + srow;
      *(float4*)&As[r * 40 + skq] = *(const float4*)&A[(size_t)(by * 128 + r) * K + k0 + skq];
      *(float4*)&Bs[r * 40 + skq] = *(const float4*)&Bt[(size_t)(bx * 128 + r) * K + k0 + skq];
    }
    __syncthreads();
    bf16x8 af[4], bf[4];
    #pragma unroll
    for (int i = 0; i < 4; ++i){
      af[i] = *(const bf16x8*)&As[(wm + i * 16 + lo) * 40 + hi * 8];
      bf[i] = *(const bf16x8*)&Bs[(wn + i * 16 + lo) * 40 + hi * 8];
    }
    #pragma unroll
    for (int mi = 0; mi < 4; ++mi)
      #pragma unroll
      for (int ni = 0; ni < 4; ++ni)
        acc[mi][ni] = __builtin_amdgcn_mfma_f32_16x16x32_bf16(af[mi], bf[ni], acc[mi][ni], 0, 0, 0);
    __syncthreads();
  }
  #pragma unroll
  for (int ni = 0; ni < 4; ++ni){
    int col = bx * 128 + wn + ni * 16 + lo;
    float bv = bias ? bias[col] : 0.f;
    #pragma unroll
    for (int mi = 0; mi < 4; ++mi){
      int row0 = by * 128 + wm + mi * 16 + hi * 4;
      #pragma unroll
      for (int r = 0; r < 4; ++r){
        float v = acc[mi][ni][r] + bv;
        OutT* p = &C[(size_t)(row0 + r) * N + col];
        if (sizeof(OutT) == 4) *(float*)p = v; else *(unsigned short*)p = f2bf(v);
      }
    }
  }
}

// ---- EW MFMA GEMM (K=32, no LDS): EW[e-rs0,:] = ea_perm[e,:] @ WeT[n,:]^T --
__global__ void k_mfma_ew(const unsigned short* __restrict__ Ap,
    const unsigned short* __restrict__ WeT, unsigned short* __restrict__ EW,
    const int* __restrict__ row_start, int c0, int c1, int N){
  int rs0 = row_start[c0], rs1 = row_start[c1];
  int e_base = rs0 + blockIdx.y * 128;
  if (e_base >= rs1) return;
  int t = threadIdx.x;
  int bx = blockIdx.x;
  int lane = t & 63, w = t >> 6;
  int wm = (w & 1) * 64, wn = (w >> 1) * 64;
  int lo = lane & 15, hi = lane >> 4;
  bf16x8 af[4], bf[4];
  #pragma unroll
  for (int i = 0; i < 4; ++i){
    int e = min(e_base + wm + i * 16 + lo, rs1 - 1);
    af[i] = *(const bf16x8*)&Ap[(size_t)e * 32 + hi * 8];
    int n = bx * 128 + wn + i * 16 + lo;
    bf[i] = *(const bf16x8*)&WeT[(size_t)n * 32 + hi * 8];
  }
  f32x4 acc[4][4] = {};
  #pragma unroll
  for (int mi = 0; mi < 4; ++mi)
    #pragma unroll
    for (int ni = 0; ni < 4; ++ni)
      acc[mi][ni] = __builtin_amdgcn_mfma_f32_16x16x32_bf16(af[mi], bf[ni], acc[mi][ni], 0, 0, 0);
  #pragma unroll
  for (int mi = 0; mi < 4; ++mi){
    int e0 = e_base + wm + mi * 16 + hi * 4;
    #pragma unroll
    for (int r = 0; r < 4; ++r){
      int e = e0 + r;
      if (e < rs1){
        #pragma unroll
        for (int ni = 0; ni < 4; ++ni){
          int col = bx * 128 + wn + ni * 16 + lo;
          EW[(size_t)(e - rs0) * N + col] = f2bf(acc[mi][ni][r]);
        }
      }
    }
  }
}

// ---- fused logit + online-softmax + aggregation (one wave per dst node) ----
template<int CH, typename OutT>   // FO = CH*256
__global__ __launch_bounds__(256) void k_fused_agg(const float* __restrict__ XL,
    const unsigned short* __restrict__ XRb, const unsigned short* __restrict__ EW,
    const int* __restrict__ csr_src, const int* __restrict__ row_start,
    const float* __restrict__ att, const float* __restrict__ bc,
    OutT* __restrict__ out, int c0){
  const int FO = CH * 256;
  int lane = threadIdx.x & 63;
  int wave = threadIdx.x >> 6;
  int n = c0 + blockIdx.x * 4 + wave;
  int rs0 = row_start[c0];
  int rs = row_start[n], re = row_start[n + 1];
  int jj = lane << 2;
  float4 xr[CH], at4[CH], acc[CH];
  #pragma unroll
  for (int c = 0; c < CH; ++c){
    xr[c] = load4(&XRb[(size_t)n * FO + (c << 8) + jj]);
    at4[c] = *(const float4*)&att[(c << 8) + jj];
    acc[c] = make_float4(0.f, 0.f, 0.f, 0.f);
  }
  float m = -1e30f, den = 0.f;
  for (int i = rs; i < re; ++i){
    int s = csr_src[i];
    const float* xp = XL + (size_t)s * FO;
    const unsigned short* ep = EW + (size_t)(i - rs0) * FO;
    float4 xl[CH];
    float tt = 0.f;
    #pragma unroll
    for (int c = 0; c < CH; ++c){
      xl[c] = *(const float4*)&xp[(c << 8) + jj];
      float4 ew = load4(&ep[(c << 8) + jj]);
      float v0 = xl[c].x + xr[c].x + ew.x;
      float v1 = xl[c].y + xr[c].y + ew.y;
      float v2 = xl[c].z + xr[c].z + ew.z;
      float v3 = xl[c].w + xr[c].w + ew.w;
      tt += at4[c].x * lrelu(v0) + at4[c].y * lrelu(v1) + at4[c].z * lrelu(v2) + at4[c].w * lrelu(v3);
    }
    tt = wredsum(tt);
    float mn = fmaxf(m, tt);
    float scale = __expf(m - mn);
    float f = __expf(tt - mn);
    den = den * scale + f;
    #pragma unroll
    for (int c = 0; c < CH; ++c){
      acc[c].x = acc[c].x * scale + f * xl[c].x;
      acc[c].y = acc[c].y * scale + f * xl[c].y;
      acc[c].z = acc[c].z * scale + f * xl[c].z;
      acc[c].w = acc[c].w * scale + f * xl[c].w;
    }
    m = mn;
  }
  float inv = 1.f / den;
  #pragma unroll
  for (int c = 0; c < CH; ++c){
    float4 b4 = *(const float4*)&bc[(c << 8) + jj];
    float4 o = make_float4(fmaxf(acc[c].x * inv + b4.x, 0.f),
                           fmaxf(acc[c].y * inv + b4.y, 0.f),
                           fmaxf(acc[c].z * inv + b4.z, 0.f),
                           fmaxf(acc[c].w * inv + b4.w, 0.f));
    store4(&out[(size_t)n * FO + (c << 8) + jj], o);
  }
}

// ---- pooling + head --------------------------------------------------------
// batch is sorted: find graph boundaries by binary search (129 entries).
__global__ void k_gstart(const int* __restrict__ batch, int* __restrict__ gstart, int N, int NG){
  int g = blockIdx.x * 256 + threadIdx.x;
  if (g > NG) return;
  int lo = 0, hi = N;
  while (lo < hi){ int mid = (lo + hi) >> 1; if (batch[mid] < g) lo = mid + 1; else hi = mid; }
  gstart[g] = lo;
}

// one block per graph; thread j accumulates feature j over the graph's node range.
__global__ void k_pool2(const float* __restrict__ H, const int* __restrict__ gstart,
                        float* __restrict__ pooled){
  int g = blockIdx.x;
  int j = threadIdx.x;
  int s = gstart[g], e = gstart[g + 1];
  float acc = 0.f;
  for (int n = s; n < e; ++n) acc += H[(size_t)n * 256 + j];
  pooled[g * 256 + j] = acc / fmaxf((float)(e - s), 1.f);
}

__global__ void k_fc1(const float* __restrict__ pooled, const float* __restrict__ w,
                      const float* __restrict__ b, float* __restrict__ z){
  int idx = blockIdx.x * 256 + threadIdx.x;
  if (idx >= 128 * 64) return;
  int g = idx >> 6, j = idx & 63;
  float acc = 0.f;
  for (int k = 0; k < 256; ++k) acc += pooled[g * 256 + k] * w[k * 64 + j];
  z[idx] = acc + b[j];
}

__global__ void k_head(const float* __restrict__ z, const float* __restrict__ bn_g,
                       const float* __restrict__ bn_b, const float* __restrict__ w2,
                       const float* __restrict__ b2, float* __restrict__ out){
  __shared__ float mu_s[64], is_s[64];
  int t = threadIdx.x;  // 128 threads
  if (t < 64){
    float mu = 0.f, m2 = 0.f;
    for (int g = 0; g < 128; ++g){ float v = z[g * 64 + t]; mu += v; m2 += v * v; }
    mu /= 128.f; m2 /= 128.f;
    float var = m2 - mu * mu;
    mu_s[t] = mu;
    is_s[t] = rsqrtf(var + 1e-5f);
  }
  __syncthreads();
  float o = b2[0];
  for (int j = 0; j < 64; ++j){
    float v = (z[t * 64 + j] - mu_s[j]) * is_s[j] * bn_g[j] + bn_b[j];
    o += fmaxf(v, 0.f) * w2[j];
  }
  out[t] = o;
}

extern "C" void kernel_launch(void* const* d_in, const int* in_sizes, int n_in,
                              void* d_out, int out_size, void* d_ws, size_t ws_size,
                              hipStream_t stream){
  const int N = 16384, E = 131072, Eaug = E + N, NG = 128;
  const float* x     = (const float*)d_in[0];
  const int*   ei    = (const int*)  d_in[1];
  const float* ea    = (const float*)d_in[2];
  const int*   batch = (const int*)  d_in[3];
  const float* Wl[3]  = {(const float*)d_in[4],  (const float*)d_in[11], (const float*)d_in[18]};
  const float* bl[3]  = {(const float*)d_in[5],  (const float*)d_in[12], (const float*)d_in[19]};
  const float* Wr[3]  = {(const float*)d_in[6],  (const float*)d_in[13], (const float*)d_in[20]};
  const float* br[3]  = {(const float*)d_in[7],  (const float*)d_in[14], (const float*)d_in[21]};
  const float* We[3]  = {(const float*)d_in[8],  (const float*)d_in[15], (const float*)d_in[22]};
  const float* att[3] = {(const float*)d_in[9],  (const float*)d_in[16], (const float*)d_in[23]};
  const float* bc[3]  = {(const float*)d_in[10], (const float*)d_in[17], (const float*)d_in[24]};
  const float* fc1_w = (const float*)d_in[25];
  const float* fc1_b = (const float*)d_in[26];
  const float* bn_g  = (const float*)d_in[27];
  const float* bn_b  = (const float*)d_in[28];
  const float* fc2_w = (const float*)d_in[29];
  const float* fc2_b = (const float*)d_in[30];
  float* out = (float*)d_out;

  char* wsb = (char*)d_ws;
  size_t off = 0;
  auto alloc = [&](size_t bytes) -> char* {
    char* p = wsb + off;
    off = (off + bytes + 255) & ~(size_t)255;
    return p;
  };
  int*   deg       = (int*)  alloc((size_t)N * 4);
  int*   fill      = (int*)  alloc((size_t)N * 4);
  int*   row_start = (int*)  alloc((size_t)(N + 1) * 4);
  int*   csr_src   = (int*)  alloc((size_t)Eaug * 4);
  int*   csr_eid   = (int*)  alloc((size_t)Eaug * 4);
  unsigned short* ea_perm = (unsigned short*)alloc((size_t)Eaug * 32 * 2);
  float* XL        = (float*)alloc((size_t)N * 1024 * 4);              // 64 MB
  unsigned short* XRb  = (unsigned short*)alloc((size_t)N * 1024 * 2); // 32 MB
  unsigned short* bufA = (unsigned short*)alloc((size_t)N * 1024 * 2); // 32 MB: Xb / L2-out
  unsigned short* bufB = (unsigned short*)alloc((size_t)N * 512 * 4);  // 32 MB: L1-out bf16 / L3-out fp32
  unsigned short* WtL  = (unsigned short*)alloc((size_t)1024 * 1024 * 2);
  unsigned short* WtR  = (unsigned short*)alloc((size_t)1024 * 1024 * 2);
  unsigned short* WeT  = (unsigned short*)alloc((size_t)1024 * 32 * 2);
  int*   gstart    = (int*)  alloc((size_t)(NG + 1) * 4);
  float* pooled    = (float*)alloc((size_t)NG * 256 * 4);
  float* zbuf      = (float*)alloc((size_t)NG * 64 * 4);
  // EW ring gets ALL remaining workspace (>= ~28 MB at the proven 204.5 MiB ws)
  size_t ewbytes = (ws_size > off) ? (ws_size - off) : 0;
  if (ewbytes > ((size_t)512 << 20)) ewbytes = (size_t)512 << 20;
  unsigned short* EWbuf = (unsigned short*)(wsb + off);

  hipMemsetAsync(deg, 0, (size_t)2 * N * 4, stream);  // deg + fill (adjacent)

  k_deg<<<E / 256, 256, 0, stream>>>(ei, deg, E);
  k_scan<<<1, 256, 0, stream>>>(deg, row_start, N);
  k_csr_self<<<N / 256, 256, 0, stream>>>(row_start, csr_src, csr_eid, N, E);
  k_csr_fill<<<E / 256, 256, 0, stream>>>(ei, row_start, fill, csr_src, csr_eid, E);
  k_loop_attr<<<N / 8, 256, 0, stream>>>(ea, csr_eid, row_start, ea_perm, N);
  k_permute_pos<<<(Eaug * 8 + 255) / 256, 256, 0, stream>>>(ea, csr_eid, ea_perm, Eaug, E);
  k_cvt_bf16<<<(N * 256 / 4) / 256, 256, 0, stream>>>(x, bufA, N * 256 / 4);

  const int fin[3] = {256, 512, 1024};
  const int fo[3]  = {512, 1024, 256};
  const unsigned short* Ain[3] = {bufA, bufB, bufA};

  for (int L = 0; L < 3; ++L){
    int FI = fin[L], FO = fo[L];
    k_transpose_bf16<<<dim3(FO / 64, FI / 64), 256, 0, stream>>>(Wl[L], WtL, FI, FO);
    k_transpose_bf16<<<dim3(FO / 64, FI / 64), 256, 0, stream>>>(Wr[L], WtR, FI, FO);
    k_transpose_we<<<(32 * FO + 255) / 256, 256, 0, stream>>>(We[L], WeT, FO);
    dim3 gg(FO / 128, N / 128);
    k_mfma_gemm<float><<<gg, 256, 0, stream>>>(Ain[L], WtL, bl[L], XL, N, FO, FI);
    k_mfma_gemm<unsigned short><<<gg, 256, 0, stream>>>(Ain[L], WtR, br[L], XRb, N, FO, FI);

    // chunk sizing from actual EW capacity: mean edges = 9*npc, keep 10*npc+4096 <= budget (>80 sigma)
    size_t budget = ewbytes / ((size_t)FO * 2);
    int npc = 4;
    while (npc < N){
      long next = (long)npc * 2;
      if (10L * next + 4096 <= (long)budget) npc = (int)next; else break;
    }
    int nchunks = N / npc;
    int ewrows = (int)((10L * npc + 4096 + 127) / 128);
    for (int c = 0; c < nchunks; ++c){
      dim3 eg(FO / 128, ewrows);
      k_mfma_ew<<<eg, 256, 0, stream>>>(ea_perm, WeT, EWbuf, row_start, c * npc, (c + 1) * npc, FO);
      if (FO == 512)
        k_fused_agg<2, unsigned short><<<npc / 4, 256, 0, stream>>>(XL, XRb, EWbuf, csr_src, row_start, att[L], bc[L], bufB, c * npc);
      else if (FO == 1024)
        k_fused_agg<4, unsigned short><<<npc / 4, 256, 0, stream>>>(XL, XRb, EWbuf, csr_src, row_start, att[L], bc[L], bufA, c * npc);
      else
        k_fused_agg<1, float><<<npc / 4, 256, 0, stream>>>(XL, XRb, EWbuf, csr_src, row_start, att[L], bc[L], (float*)bufB, c * npc);
    }
  }

  k_gstart<<<1, 256, 0, stream>>>(batch, gstart, N, NG);
  k_pool2<<<NG, 256, 0, stream>>>((const float*)bufB, gstart, pooled);
  k_fc1<<<32, 256, 0, stream>>>(pooled, fc1_w, fc1_b, zbuf);
  k_head<<<1, 128, 0, stream>>>(zbuf, bn_g, bn_b, fc2_w, fc2_b, out);
}

// Round 7
// 765.014 us; speedup vs baseline: 16.1679x; 1.2136x over previous
//
#include <hip/hip_runtime.h>
#include <hip/hip_bf16.h>
#include <math.h>

#define NEG_SLOPE 0.2f

typedef short bf16x8 __attribute__((ext_vector_type(8)));
typedef float f32x4 __attribute__((ext_vector_type(4)));

__device__ __forceinline__ float wredsum(float v){
  #pragma unroll
  for (int o = 32; o; o >>= 1) v += __shfl_xor(v, o, 64);
  return v;
}
__device__ __forceinline__ float lrelu(float x){ return x >= 0.f ? x : NEG_SLOPE * x; }
__device__ __forceinline__ unsigned short f2bf(float f){
  __hip_bfloat16 h = __float2bfloat16(f);
  return *(unsigned short*)&h;
}
__device__ __forceinline__ float bf2f(unsigned short u){
  return __uint_as_float((unsigned)u << 16);
}

__device__ __forceinline__ float4 load4(const float* p){ return *(const float4*)p; }
__device__ __forceinline__ float4 load4(const unsigned short* p){
  ushort4 u = *(const ushort4*)p;
  return make_float4(bf2f(u.x), bf2f(u.y), bf2f(u.z), bf2f(u.w));
}
__device__ __forceinline__ void store4(float* p, float4 v){ *(float4*)p = v; }
__device__ __forceinline__ void store4(unsigned short* p, float4 v){
  ushort4 o; o.x = f2bf(v.x); o.y = f2bf(v.y); o.z = f2bf(v.z); o.w = f2bf(v.w);
  *(ushort4*)p = o;
}

// ---- CSR construction ------------------------------------------------------
__global__ void k_deg(const int* __restrict__ ei, int* __restrict__ deg, int E){
  int e = blockIdx.x * 256 + threadIdx.x;
  if (e >= E) return;
  atomicAdd(&deg[ei[E + e]], 1);
}

// row width = deg[n] + 1 (self loop).  N = 16384 = 256 * 64, single block scan.
__global__ void k_scan(const int* __restrict__ deg, int* __restrict__ row_start, int N){
  __shared__ int s[256];
  int t = threadIdx.x;
  int base = t * 64;
  int sum = 0;
  for (int i = 0; i < 64; ++i) sum += deg[base + i] + 1;
  s[t] = sum;
  __syncthreads();
  for (int off = 1; off < 256; off <<= 1){
    int v = (t >= off) ? s[t - off] : 0;
    __syncthreads();
    s[t] += v;
    __syncthreads();
  }
  int run = s[t] - sum;   // exclusive
  for (int i = 0; i < 64; ++i){ row_start[base + i] = run; run += deg[base + i] + 1; }
  if (t == 255) row_start[N] = run;
}

__global__ void k_csr_self(const int* __restrict__ row_start, int* __restrict__ csr_src,
                           int* __restrict__ csr_eid, int N, int E){
  int n = blockIdx.x * 256 + threadIdx.x;
  if (n >= N) return;
  int p = row_start[n];
  csr_src[p] = n;          // self loop in slot 0
  csr_eid[p] = E;          // sentinel: not a real edge
}

__global__ void k_csr_fill(const int* __restrict__ ei, const int* __restrict__ row_start,
                           int* __restrict__ fill, int* __restrict__ csr_src,
                           int* __restrict__ csr_eid, int E){
  int e = blockIdx.x * 256 + threadIdx.x;
  if (e >= E) return;
  int dst = ei[E + e];
  int p = row_start[dst] + 1 + atomicAdd(&fill[dst], 1);
  csr_src[p] = ei[e];
  csr_eid[p] = e;
}

// self-loop attr = mean of incoming ea rows; written straight into ea_perm slot 0.
__global__ void k_loop_attr(const float* __restrict__ ea, const int* __restrict__ csr_eid,
                            const int* __restrict__ row_start,
                            unsigned short* __restrict__ ea_perm, int N){
  int t = threadIdx.x;
  int half = t >> 5, k = t & 31;
  int n = blockIdx.x * 8 + half;
  if (n >= N) return;
  int rs = row_start[n], re = row_start[n + 1];
  float sum = 0.f;
  for (int i = rs + 1; i < re; ++i){
    int e = csr_eid[i];
    sum += ea[(size_t)e * 32 + k];
  }
  float d = (float)max(re - rs - 1, 1);
  ea_perm[(size_t)rs * 32 + k] = f2bf(sum / d);
}

// non-self rows: ea_perm[p] = bf16(ea[csr_eid[p]])
__global__ void k_permute_pos(const float* __restrict__ ea, const int* __restrict__ csr_eid,
                              unsigned short* __restrict__ ea_perm, int Eaug, int E){
  int idx = blockIdx.x * 256 + threadIdx.x;
  int p = idx >> 3, q = idx & 7;
  if (p >= Eaug) return;
  int e = csr_eid[p];
  if (e >= E) return;
  float4 v = ((const float4*)(ea + (size_t)e * 32))[q];
  ushort4 o;
  o.x = f2bf(v.x); o.y = f2bf(v.y); o.z = f2bf(v.z); o.w = f2bf(v.w);
  *(ushort4*)&ea_perm[(size_t)p * 32 + q * 4] = o;
}

// ---- dtype prep ------------------------------------------------------------
__global__ void k_cvt_bf16(const float* __restrict__ in, unsigned short* __restrict__ out, int n4){
  int idx = blockIdx.x * 256 + threadIdx.x;
  if (idx >= n4) return;
  float4 v = *(const float4*)&in[idx * 4];
  store4(&out[idx * 4], v);
}

// W[K,N] fp32 -> Wt[N,K] bf16, K,N multiples of 64.  blockIdx.z selects (W0->Wt0, W1->Wt1).
__global__ __launch_bounds__(256) void k_transpose2_bf16(const float* __restrict__ W0,
    const float* __restrict__ W1, unsigned short* __restrict__ Wt0,
    unsigned short* __restrict__ Wt1, int K, int N){
  __shared__ float tile[64][65];
  const float* W = blockIdx.z ? W1 : W0;
  unsigned short* Wt = blockIdx.z ? Wt1 : Wt0;
  int n0 = blockIdx.x * 64, k0 = blockIdx.y * 64;
  int col = threadIdx.x & 63, rq = threadIdx.x >> 6;
  #pragma unroll
  for (int i = 0; i < 16; ++i){
    int r = rq * 16 + i;
    tile[r][col] = W[(size_t)(k0 + r) * N + n0 + col];
  }
  __syncthreads();
  #pragma unroll
  for (int i = 0; i < 16; ++i){
    int r = rq * 16 + i;
    Wt[(size_t)(n0 + r) * K + k0 + col] = f2bf(tile[col][r]);
  }
}

__global__ void k_transpose_we(const float* __restrict__ We, unsigned short* __restrict__ WeT, int FO){
  int idx = blockIdx.x * 256 + threadIdx.x;
  if (idx >= 32 * FO) return;
  int k = idx / FO, n = idx % FO;
  WeT[n * 32 + k] = f2bf(We[idx]);
}

// ---- bf16 MFMA GEMM: C[M,N] = A[M,K] @ Bt[N,K]^T + bias --------------------
template<typename OutT>
__global__ void k_mfma_gemm(const unsigned short* __restrict__ A,
    const unsigned short* __restrict__ Bt, const float* __restrict__ bias,
    OutT* __restrict__ C, int M, int N, int K){
  __shared__ unsigned short As[128 * 40];
  __shared__ unsigned short Bs[128 * 40];
  int t = threadIdx.x;
  int bx = blockIdx.x, by = blockIdx.y;
  int lane = t & 63, w = t >> 6;
  int wm = (w & 1) * 64, wn = (w >> 1) * 64;
  int lo = lane & 15, hi = lane >> 4;
  int srow = t >> 2, skq = (t & 3) * 8;
  f32x4 acc[4][4] = {};
  for (int k0 = 0; k0 < K; k0 += 32){
    #pragma unroll
    for (int p = 0; p < 2; ++p){
      int r = p * 64 + srow;
      *(float4*)&As[r * 40 + skq] = *(const float4*)&A[(size_t)(by * 128 + r) * K + k0 + skq];
      *(float4*)&Bs[r * 40 + skq] = *(const float4*)&Bt[(size_t)(bx * 128 + r) * K + k0 + skq];
    }
    __syncthreads();
    bf16x8 af[4], bf[4];
    #pragma unroll
    for (int i = 0; i < 4; ++i){
      af[i] = *(const bf16x8*)&As[(wm + i * 16 + lo) * 40 + hi * 8];
      bf[i] = *(const bf16x8*)&Bs[(wn + i * 16 + lo) * 40 + hi * 8];
    }
    #pragma unroll
    for (int mi = 0; mi < 4; ++mi)
      #pragma unroll
      for (int ni = 0; ni < 4; ++ni)
        acc[mi][ni] = __builtin_amdgcn_mfma_f32_16x16x32_bf16(af[mi], bf[ni], acc[mi][ni], 0, 0, 0);
    __syncthreads();
  }
  #pragma unroll
  for (int ni = 0; ni < 4; ++ni){
    int col = bx * 128 + wn + ni * 16 + lo;
    float bv = bias ? bias[col] : 0.f;
    #pragma unroll
    for (int mi = 0; mi < 4; ++mi){
      int row0 = by * 128 + wm + mi * 16 + hi * 4;
      #pragma unroll
      for (int r = 0; r < 4; ++r){
        float v = acc[mi][ni][r] + bv;
        OutT* p = &C[(size_t)(row0 + r) * N + col];
        if (sizeof(OutT) == 4) *(float*)p = v; else *(unsigned short*)p = f2bf(v);
      }
    }
  }
}

// ---- EW MFMA GEMM (K=32, no LDS): EW[e-rs0,:] = ea_perm[e,:] @ WeT[n,:]^T --
__global__ void k_mfma_ew(const unsigned short* __restrict__ Ap,
    const unsigned short* __restrict__ WeT, unsigned short* __restrict__ EW,
    const int* __restrict__ row_start, int c0, int c1, int N){
  int rs0 = row_start[c0], rs1 = row_start[c1];
  int e_base = rs0 + blockIdx.y * 128;
  if (e_base >= rs1) return;
  int t = threadIdx.x;
  int bx = blockIdx.x;
  int lane = t & 63, w = t >> 6;
  int wm = (w & 1) * 64, wn = (w >> 1) * 64;
  int lo = lane & 15, hi = lane >> 4;
  bf16x8 af[4], bf[4];
  #pragma unroll
  for (int i = 0; i < 4; ++i){
    int e = min(e_base + wm + i * 16 + lo, rs1 - 1);
    af[i] = *(const bf16x8*)&Ap[(size_t)e * 32 + hi * 8];
    int n = bx * 128 + wn + i * 16 + lo;
    bf[i] = *(const bf16x8*)&WeT[(size_t)n * 32 + hi * 8];
  }
  f32x4 acc[4][4] = {};
  #pragma unroll
  for (int mi = 0; mi < 4; ++mi)
    #pragma unroll
    for (int ni = 0; ni < 4; ++ni)
      acc[mi][ni] = __builtin_amdgcn_mfma_f32_16x16x32_bf16(af[mi], bf[ni], acc[mi][ni], 0, 0, 0);
  #pragma unroll
  for (int mi = 0; mi < 4; ++mi){
    int e0 = e_base + wm + mi * 16 + hi * 4;
    #pragma unroll
    for (int r = 0; r < 4; ++r){
      int e = e0 + r;
      if (e < rs1){
        #pragma unroll
        for (int ni = 0; ni < 4; ++ni){
          int col = bx * 128 + wn + ni * 16 + lo;
          EW[(size_t)(e - rs0) * N + col] = f2bf(acc[mi][ni][r]);
        }
      }
    }
  }
}

// ---- fused logit + online-softmax + aggregation (one wave per dst node) ----
// XL is bf16 now (halves the per-edge gather traffic); accumulate fp32.
template<int CH, typename OutT>   // FO = CH*256
__global__ __launch_bounds__(256) void k_fused_agg(const unsigned short* __restrict__ XL,
    const unsigned short* __restrict__ XRb, const unsigned short* __restrict__ EW,
    const int* __restrict__ csr_src, const int* __restrict__ row_start,
    const float* __restrict__ att, const float* __restrict__ bc,
    OutT* __restrict__ out, int c0){
  const int FO = CH * 256;
  int lane = threadIdx.x & 63;
  int wave = threadIdx.x >> 6;
  int n = c0 + blockIdx.x * 4 + wave;
  int rs0 = row_start[c0];
  int rs = row_start[n], re = row_start[n + 1];
  int jj = lane << 2;
  float4 xr[CH], at4[CH], acc[CH];
  #pragma unroll
  for (int c = 0; c < CH; ++c){
    xr[c] = load4(&XRb[(size_t)n * FO + (c << 8) + jj]);
    at4[c] = *(const float4*)&att[(c << 8) + jj];
    acc[c] = make_float4(0.f, 0.f, 0.f, 0.f);
  }
  float m = -1e30f, den = 0.f;
  for (int i = rs; i < re; ++i){
    int s = csr_src[i];
    const unsigned short* xp = XL + (size_t)s * FO;
    const unsigned short* ep = EW + (size_t)(i - rs0) * FO;
    float4 xl[CH];
    float tt = 0.f;
    #pragma unroll
    for (int c = 0; c < CH; ++c){
      xl[c] = load4(&xp[(c << 8) + jj]);
      float4 ew = load4(&ep[(c << 8) + jj]);
      float v0 = xl[c].x + xr[c].x + ew.x;
      float v1 = xl[c].y + xr[c].y + ew.y;
      float v2 = xl[c].z + xr[c].z + ew.z;
      float v3 = xl[c].w + xr[c].w + ew.w;
      tt += at4[c].x * lrelu(v0) + at4[c].y * lrelu(v1) + at4[c].z * lrelu(v2) + at4[c].w * lrelu(v3);
    }
    tt = wredsum(tt);
    float mn = fmaxf(m, tt);
    float scale = __expf(m - mn);
    float f = __expf(tt - mn);
    den = den * scale + f;
    #pragma unroll
    for (int c = 0; c < CH; ++c){
      acc[c].x = acc[c].x * scale + f * xl[c].x;
      acc[c].y = acc[c].y * scale + f * xl[c].y;
      acc[c].z = acc[c].z * scale + f * xl[c].z;
      acc[c].w = acc[c].w * scale + f * xl[c].w;
    }
    m = mn;
  }
  float inv = 1.f / den;
  #pragma unroll
  for (int c = 0; c < CH; ++c){
    float4 b4 = *(const float4*)&bc[(c << 8) + jj];
    float4 o = make_float4(fmaxf(acc[c].x * inv + b4.x, 0.f),
                           fmaxf(acc[c].y * inv + b4.y, 0.f),
                           fmaxf(acc[c].z * inv + b4.z, 0.f),
                           fmaxf(acc[c].w * inv + b4.w, 0.f));
    store4(&out[(size_t)n * FO + (c << 8) + jj], o);
  }
}

// ---- pooling + head --------------------------------------------------------
__global__ void k_gstart(const int* __restrict__ batch, int* __restrict__ gstart, int N, int NG){
  int g = blockIdx.x * 256 + threadIdx.x;
  if (g > NG) return;
  int lo = 0, hi = N;
  while (lo < hi){ int mid = (lo + hi) >> 1; if (batch[mid] < g) lo = mid + 1; else hi = mid; }
  gstart[g] = lo;
}

__global__ void k_pool2(const float* __restrict__ H, const int* __restrict__ gstart,
                        float* __restrict__ pooled){
  int g = blockIdx.x;
  int j = threadIdx.x;
  int s = gstart[g], e = gstart[g + 1];
  float acc = 0.f;
  for (int n = s; n < e; ++n) acc += H[(size_t)n * 256 + j];
  pooled[g * 256 + j] = acc / fmaxf((float)(e - s), 1.f);
}

__global__ void k_fc1(const float* __restrict__ pooled, const float* __restrict__ w,
                      const float* __restrict__ b, float* __restrict__ z){
  int idx = blockIdx.x * 256 + threadIdx.x;
  if (idx >= 128 * 64) return;
  int g = idx >> 6, j = idx & 63;
  float acc = 0.f;
  for (int k = 0; k < 256; ++k) acc += pooled[g * 256 + k] * w[k * 64 + j];
  z[idx] = acc + b[j];
}

__global__ void k_head(const float* __restrict__ z, const float* __restrict__ bn_g,
                       const float* __restrict__ bn_b, const float* __restrict__ w2,
                       const float* __restrict__ b2, float* __restrict__ out){
  __shared__ float mu_s[64], is_s[64];
  int t = threadIdx.x;  // 128 threads
  if (t < 64){
    float mu = 0.f, m2 = 0.f;
    for (int g = 0; g < 128; ++g){ float v = z[g * 64 + t]; mu += v; m2 += v * v; }
    mu /= 128.f; m2 /= 128.f;
    float var = m2 - mu * mu;
    mu_s[t] = mu;
    is_s[t] = rsqrtf(var + 1e-5f);
  }
  __syncthreads();
  float o = b2[0];
  for (int j = 0; j < 64; ++j){
    float v = (z[t * 64 + j] - mu_s[j]) * is_s[j] * bn_g[j] + bn_b[j];
    o += fmaxf(v, 0.f) * w2[j];
  }
  out[t] = o;
}

extern "C" void kernel_launch(void* const* d_in, const int* in_sizes, int n_in,
                              void* d_out, int out_size, void* d_ws, size_t ws_size,
                              hipStream_t stream){
  const int N = 16384, E = 131072, Eaug = E + N, NG = 128;
  const float* x     = (const float*)d_in[0];
  const int*   ei    = (const int*)  d_in[1];
  const float* ea    = (const float*)d_in[2];
  const int*   batch = (const int*)  d_in[3];
  const float* Wl[3]  = {(const float*)d_in[4],  (const float*)d_in[11], (const float*)d_in[18]};
  const float* bl[3]  = {(const float*)d_in[5],  (const float*)d_in[12], (const float*)d_in[19]};
  const float* Wr[3]  = {(const float*)d_in[6],  (const float*)d_in[13], (const float*)d_in[20]};
  const float* br[3]  = {(const float*)d_in[7],  (const float*)d_in[14], (const float*)d_in[21]};
  const float* We[3]  = {(const float*)d_in[8],  (const float*)d_in[15], (const float*)d_in[22]};
  const float* att[3] = {(const float*)d_in[9],  (const float*)d_in[16], (const float*)d_in[23]};
  const float* bc[3]  = {(const float*)d_in[10], (const float*)d_in[17], (const float*)d_in[24]};
  const float* fc1_w = (const float*)d_in[25];
  const float* fc1_b = (const float*)d_in[26];
  const float* bn_g  = (const float*)d_in[27];
  const float* bn_b  = (const float*)d_in[28];
  const float* fc2_w = (const float*)d_in[29];
  const float* fc2_b = (const float*)d_in[30];
  float* out = (float*)d_out;

  char* wsb = (char*)d_ws;
  size_t off = 0;
  auto alloc = [&](size_t bytes) -> char* {
    char* p = wsb + off;
    off = (off + bytes + 255) & ~(size_t)255;
    return p;
  };
  int*   deg       = (int*)  alloc((size_t)N * 4);
  int*   fill      = (int*)  alloc((size_t)N * 4);
  int*   row_start = (int*)  alloc((size_t)(N + 1) * 4);
  int*   csr_src   = (int*)  alloc((size_t)Eaug * 4);
  int*   csr_eid   = (int*)  alloc((size_t)Eaug * 4);
  unsigned short* ea_perm = (unsigned short*)alloc((size_t)Eaug * 32 * 2);
  unsigned short* XL   = (unsigned short*)alloc((size_t)N * 1024 * 2); // 32 MB (bf16 now)
  unsigned short* XRb  = (unsigned short*)alloc((size_t)N * 1024 * 2); // 32 MB
  unsigned short* bufA = (unsigned short*)alloc((size_t)N * 1024 * 2); // 32 MB: Xb / L2-out
  unsigned short* bufB = (unsigned short*)alloc((size_t)N * 512 * 4);  // 32 MB: L1-out bf16 / L3-out fp32
  unsigned short* WtL  = (unsigned short*)alloc((size_t)1024 * 1024 * 2);
  unsigned short* WtR  = (unsigned short*)alloc((size_t)1024 * 1024 * 2);
  unsigned short* WeT  = (unsigned short*)alloc((size_t)1024 * 32 * 2);
  int*   gstart    = (int*)  alloc((size_t)(NG + 1) * 4);
  float* pooled    = (float*)alloc((size_t)NG * 256 * 4);
  float* zbuf      = (float*)alloc((size_t)NG * 64 * 4);
  // EW ring gets ALL remaining workspace
  size_t ewbytes = (ws_size > off) ? (ws_size - off) : 0;
  if (ewbytes > ((size_t)512 << 20)) ewbytes = (size_t)512 << 20;
  unsigned short* EWbuf = (unsigned short*)(wsb + off);

  hipMemsetAsync(deg, 0, (size_t)2 * N * 4, stream);  // deg + fill (adjacent)

  k_deg<<<E / 256, 256, 0, stream>>>(ei, deg, E);
  k_scan<<<1, 256, 0, stream>>>(deg, row_start, N);
  k_csr_self<<<N / 256, 256, 0, stream>>>(row_start, csr_src, csr_eid, N, E);
  k_csr_fill<<<E / 256, 256, 0, stream>>>(ei, row_start, fill, csr_src, csr_eid, E);
  k_loop_attr<<<N / 8, 256, 0, stream>>>(ea, csr_eid, row_start, ea_perm, N);
  k_permute_pos<<<(Eaug * 8 + 255) / 256, 256, 0, stream>>>(ea, csr_eid, ea_perm, Eaug, E);
  k_cvt_bf16<<<(N * 256 / 4) / 256, 256, 0, stream>>>(x, bufA, N * 256 / 4);

  const int fin[3] = {256, 512, 1024};
  const int fo[3]  = {512, 1024, 256};
  const unsigned short* Ain[3] = {bufA, bufB, bufA};

  for (int L = 0; L < 3; ++L){
    int FI = fin[L], FO = fo[L];
    k_transpose2_bf16<<<dim3(FO / 64, FI / 64, 2), 256, 0, stream>>>(Wl[L], Wr[L], WtL, WtR, FI, FO);
    k_transpose_we<<<(32 * FO + 255) / 256, 256, 0, stream>>>(We[L], WeT, FO);
    dim3 gg(FO / 128, N / 128);
    k_mfma_gemm<unsigned short><<<gg, 256, 0, stream>>>(Ain[L], WtL, bl[L], XL, N, FO, FI);
    k_mfma_gemm<unsigned short><<<gg, 256, 0, stream>>>(Ain[L], WtR, br[L], XRb, N, FO, FI);

    // chunk sizing from actual EW capacity: mean edges = 9*npc, keep 10*npc+4096 <= budget
    size_t budget = ewbytes / ((size_t)FO * 2);
    int npc = 4;
    while (npc < N){
      long next = (long)npc * 2;
      if (10L * next + 4096 <= (long)budget) npc = (int)next; else break;
    }
    int nchunks = N / npc;
    int ewrows = (int)((10L * npc + 4096 + 127) / 128);
    for (int c = 0; c < nchunks; ++c){
      dim3 eg(FO / 128, ewrows);
      k_mfma_ew<<<eg, 256, 0, stream>>>(ea_perm, WeT, EWbuf, row_start, c * npc, (c + 1) * npc, FO);
      if (FO == 512)
        k_fused_agg<2, unsigned short><<<npc / 4, 256, 0, stream>>>(XL, XRb, EWbuf, csr_src, row_start, att[L], bc[L], bufB, c * npc);
      else if (FO == 1024)
        k_fused_agg<4, unsigned short><<<npc / 4, 256, 0, stream>>>(XL, XRb, EWbuf, csr_src, row_start, att[L], bc[L], bufA, c * npc);
      else
        k_fused_agg<1, float><<<npc / 4, 256, 0, stream>>>(XL, XRb, EWbuf, csr_src, row_start, att[L], bc[L], (float*)bufB, c * npc);
    }
  }

  k_gstart<<<1, 256, 0, stream>>>(batch, gstart, N, NG);
  k_pool2<<<NG, 256, 0, stream>>>((const float*)bufB, gstart, pooled);
  k_fc1<<<32, 256, 0, stream>>>(pooled, fc1_w, fc1_b, zbuf);
  k_head<<<1, 128, 0, stream>>>(zbuf, bn_g, bn_b, fc2_w, fc2_b, out);
}